// Round 12
// baseline (528.412 us; speedup 1.0000x reference)
//
#include <hip/hip_runtime.h>
#include <cmath>

#define T_SAMPLE 300
#define NCHUNK 75   // T / 4

struct RefK { float v[10]; };

// One step of the SLAYER spike recurrence. buf[0..9] = pending refractory.
__device__ __forceinline__ unsigned char spike_step(float u, float* buf, const RefK& rk) {
    const float um = u + buf[0];
    const bool fire = um >= 10.0f;
    const float ev = fire ? 1.0f : 0.0f;
#pragma unroll
    for (int r = 0; r < 9; ++r) buf[r] = fmaf(ev, rk.v[r], buf[r + 1]);
    buf[9] = ev * rk.v[9];
    return fire ? (unsigned char)1 : (unsigned char)0;
}

// ---------------------------------------------------------------------------
// transpose input [B,2,34,34,T] f32 ({0,1}) -> X[tchunk][n][4] u8, n = b,c,y,x
// ---------------------------------------------------------------------------
__global__ __launch_bounds__(256) void transpose_in_kernel(
    const float* __restrict__ In, unsigned int* __restrict__ X)
{
    __shared__ unsigned int lds[16 * NCHUNK];
    const int blk = blockIdx.x;          // 1156 blocks x 16 neurons
    const int tn = threadIdx.x >> 4;     // 0..15 neuron
    const int tq = threadIdx.x & 15;     // 0..15 t-group
    const size_t n = (size_t)blk * 16 + tn;
#pragma unroll
    for (int p = 0; p < 5; ++p) {
        const int ch = p * 16 + tq;
        if (ch < NCHUNK) {
            const float4 v = *(const float4*)(In + n * T_SAMPLE + ch * 4);
            unsigned int u = (v.x != 0.f ? 1u : 0u) | (v.y != 0.f ? 0x100u : 0u) |
                             (v.z != 0.f ? 0x10000u : 0u) | (v.w != 0.f ? 0x1000000u : 0u);
            lds[tn * NCHUNK + ch] = u;
        }
    }
    __syncthreads();
    for (int idx = threadIdx.x; idx < 16 * NCHUNK; idx += 256) {
        const int ch = idx >> 4, t2 = idx & 15;
        X[(size_t)ch * 18496 + blk * 16 + t2] = lds[t2 * NCHUNK + ch];
    }
}

// ---------------------------------------------------------------------------
// conv_u (R9 config - best measured): per-timestep 2D conv (pad=1), 4
// timesteps/thread, float4 LDS tile with padded row stride EWP=EW+1, CSPLIT
// ascending-c staging passes (FMA order preserved) to cap LDS footprint.
// Grid: x = tchunk, y = tile*OG+og, z = local batch (nbl runtime).
// ---------------------------------------------------------------------------
template <int IC, int OC, int K, int OH, int OW, int IH, int IW, int OPT, int CSPLIT>
__global__ __launch_bounds__(256) void conv_u_kernel(
    const uchar4* __restrict__ in_, const float* __restrict__ W,
    float4* __restrict__ U, int b0, int nbl)
{
    constexpr int TH = 8, TW = 8;
    constexpr int EH = TH + K - 1, EW = TW + K - 1;
    constexpr int EWP = EW + 1;          // padded row stride (odd)
    constexpr int NTX = OW / TW, NTY = OH / TH, NT = NTX * NTY;
    constexpr int KK = K * K;
    constexpr int ICH = IC / CSPLIT;
    constexpr int ES = ICH * EH * EW;    // staged elements per split
    constexpr int PLANE_IN = 8 * IC * IH * IW;   // full-batch chunk plane (uchar4)
    const int PLANE_U = nbl * OC * OH * OW;      // slice chunk plane (float4)

    __shared__ float4 tile[ICH * EH * EWP];

    const int tc = blockIdx.x;
    const int by = blockIdx.y;
    const int til = by % NT;
    const int og = by / NT;
    const int ty = til / NTX, tx = til % NTX;
    const int bl = blockIdx.z;
    const int b = b0 + bl;
    const int tid = threadIdx.x;
    const int wave = tid >> 6, lane = tid & 63;
    const int py = lane >> 3, px = lane & 7;

    const int iy0 = ty * TH - 1, ix0 = tx * TW - 1;  // PAD = 1
    const uchar4* ib = in_ + (size_t)tc * PLANE_IN + (size_t)b * IC * IH * IW;

    float acc[OPT][4];
#pragma unroll
    for (int j = 0; j < OPT; ++j)
#pragma unroll
        for (int k = 0; k < 4; ++k) acc[j][k] = 0.f;

    int ob = (og * 4 + wave) * OPT;
    ob = __builtin_amdgcn_readfirstlane(ob);   // wave-uniform -> scalar weight loads
    const float* Wp = W + (size_t)ob * IC * KK;

    for (int s = 0; s < CSPLIT; ++s) {
        if (s > 0) __syncthreads();          // prev split's reads done
        for (int e = tid; e < ES; e += 256) {
            const int cl = e / (EH * EW);
            const int r = e % (EH * EW);
            const int iy = r / EW, ix = r % EW;
            const int gy = iy0 + iy, gx = ix0 + ix;
            float4 v = make_float4(0.f, 0.f, 0.f, 0.f);
            if ((unsigned)gy < (unsigned)IH && (unsigned)gx < (unsigned)IW) {
                const uchar4 sv = ib[((s * ICH + cl) * IH + gy) * IW + gx];
                v = make_float4((float)sv.x, (float)sv.y, (float)sv.z, (float)sv.w);
            }
            tile[(cl * EH + iy) * EWP + ix] = v;
        }
        __syncthreads();

        for (int cl = 0; cl < ICH; ++cl) {
            const int c = s * ICH + cl;
#pragma unroll
            for (int dy = 0; dy < K; ++dy) {
                float wr[OPT][K];
#pragma unroll
                for (int j = 0; j < OPT; ++j)
#pragma unroll
                    for (int dx = 0; dx < K; ++dx)
                        wr[j][dx] = Wp[(j * IC + c) * KK + dy * K + dx];
#pragma unroll
                for (int dx = 0; dx < K; ++dx) {
                    const float4 v = tile[((cl * EH) + py + dy) * EWP + (px + dx)];
#pragma unroll
                    for (int j = 0; j < OPT; ++j) {
                        const float w = wr[j][dx];
                        acc[j][0] = fmaf(w, v.x, acc[j][0]);
                        acc[j][1] = fmaf(w, v.y, acc[j][1]);
                        acc[j][2] = fmaf(w, v.z, acc[j][2]);
                        acc[j][3] = fmaf(w, v.w, acc[j][3]);
                    }
                }
            }
        }
    }

    const int y = ty * TH + py, x = tx * TW + px;
#pragma unroll
    for (int j = 0; j < OPT; ++j) {
        const int nb = ((bl * OC + (ob + j)) * OH + y) * OW + x;
        U[(size_t)tc * PLANE_U + nb] = make_float4(acc[j][0], acc[j][1], acc[j][2], acc[j][3]);
    }
}

// ---------------------------------------------------------------------------
// fused spike -> pool(2)*11 -> spike: reads u (float4/chunk) at the 4 source
// neurons of one pooled site, runs 4 input recurrences + pool + output
// recurrence in-register. Eliminates the intermediate spike buffer entirely.
// Bit-exact vs separate kernels (same spike_step chains; int pool sum exact).
// Ring-4 prefetch x 4 streams (same-base imm-offset loads).
// ---------------------------------------------------------------------------
template <int C, int H, int W>
__global__ __launch_bounds__(64) void spike_pool_spike_kernel(
    const float4* __restrict__ U, uchar4* __restrict__ Sout,
    int nbl, int sout_stride, int soff, RefK rk)
{
    constexpr int H2 = H / 2, W2 = W / 2;
    const int n2 = blockIdx.x * 64 + threadIdx.x;   // pooled index in slice
    const int x2 = n2 % W2;
    const int y2 = (n2 / W2) % H2;
    const int c = (n2 / (W2 * H2)) % C;
    const int bl = n2 / (W2 * H2 * C);
    const int nn = nbl * C * H * W;                  // u chunk stride (float4)
    const float4* ub = U + (((bl * C + c) * H + 2 * y2) * W + 2 * x2);
    uchar4* q = Sout + soff + n2;

    float b00[10], b01[10], b10[10], b11[10], bo[10];
#pragma unroll
    for (int r = 0; r < 10; ++r) { b00[r] = b01[r] = b10[r] = b11[r] = bo[r] = 0.f; }

    float4 r00[4], r01[4], r10[4], r11[4];
#pragma unroll
    for (int r = 0; r < 4; ++r) {
        const float4* p = ub + (size_t)r * nn;
        r00[r] = p[0];      r01[r] = p[1];
        r10[r] = p[W];      r11[r] = p[W + 1];
    }

    for (int ch = 0; ch < NCHUNK; ++ch) {
        const int sl = ch & 3;
        const float4 c00 = r00[sl], c01 = r01[sl], c10 = r10[sl], c11 = r11[sl];
        const int pf = (ch + 4 < NCHUNK) ? ch + 4 : NCHUNK - 1;
        {
            const float4* p = ub + (size_t)pf * nn;
            r00[sl] = p[0];      r01[sl] = p[1];
            r10[sl] = p[W];      r11[sl] = p[W + 1];
        }
        uchar4 o;
        {
            const int s = (int)spike_step(c00.x, b00, rk) + (int)spike_step(c01.x, b01, rk)
                        + (int)spike_step(c10.x, b10, rk) + (int)spike_step(c11.x, b11, rk);
            o.x = spike_step(11.0f * (float)s, bo, rk);
        }
        {
            const int s = (int)spike_step(c00.y, b00, rk) + (int)spike_step(c01.y, b01, rk)
                        + (int)spike_step(c10.y, b10, rk) + (int)spike_step(c11.y, b11, rk);
            o.y = spike_step(11.0f * (float)s, bo, rk);
        }
        {
            const int s = (int)spike_step(c00.z, b00, rk) + (int)spike_step(c01.z, b01, rk)
                        + (int)spike_step(c10.z, b10, rk) + (int)spike_step(c11.z, b11, rk);
            o.z = spike_step(11.0f * (float)s, bo, rk);
        }
        {
            const int s = (int)spike_step(c00.w, b00, rk) + (int)spike_step(c01.w, b01, rk)
                        + (int)spike_step(c10.w, b10, rk) + (int)spike_step(c11.w, b11, rk);
            o.w = spike_step(11.0f * (float)s, bo, rk);
        }
        q[(size_t)ch * sout_stride] = o;
    }
}

// ---------------------------------------------------------------------------
// spike: per-neuron scan. float4 per chunk in, uchar4 per chunk out. Ring-8.
// ---------------------------------------------------------------------------
__global__ __launch_bounds__(64) void spike_kernel(
    const float4* __restrict__ U, uchar4* __restrict__ S,
    int nneur, int sstride, int soff, RefK rk)
{
    const int n = blockIdx.x * 64 + threadIdx.x;
    const float4* up = U + n;
    uchar4* sp = S + soff + n;
    float buf[10];
#pragma unroll
    for (int r = 0; r < 10; ++r) buf[r] = 0.f;

    float4 ring[8];
#pragma unroll
    for (int r = 0; r < 8; ++r) ring[r] = up[(size_t)r * nneur];

#pragma unroll 8
    for (int ch = 0; ch < 72; ++ch) {
        const float4 cur = ring[ch & 7];
        const int pf = (ch + 8 < NCHUNK) ? ch + 8 : NCHUNK - 1;
        ring[ch & 7] = up[(size_t)pf * nneur];
        uchar4 o;
        o.x = spike_step(cur.x, buf, rk);
        o.y = spike_step(cur.y, buf, rk);
        o.z = spike_step(cur.z, buf, rk);
        o.w = spike_step(cur.w, buf, rk);
        sp[(size_t)ch * sstride] = o;
    }
#pragma unroll
    for (int ch = 72; ch < NCHUNK; ++ch) {
        const float4 cur = ring[ch & 7];
        uchar4 o;
        o.x = spike_step(cur.x, buf, rk);
        o.y = spike_step(cur.y, buf, rk);
        o.z = spike_step(cur.z, buf, rk);
        o.w = spike_step(cur.w, buf, rk);
        sp[(size_t)ch * sstride] = o;
    }
}

// ---------------------------------------------------------------------------
// dense u: U6[tc][b*10+o][4] = sum_site wfc[o,site] * s5[tc][b*4096+site][4]
// ---------------------------------------------------------------------------
__global__ __launch_bounds__(64) void dense_u_kernel(
    const uchar4* __restrict__ S5, const float* __restrict__ WFC,
    float4* __restrict__ U6)
{
    const int tc = blockIdx.x, o = blockIdx.y, b = blockIdx.z;
    const int lane = threadIdx.x;
    float a0 = 0.f, a1 = 0.f, a2 = 0.f, a3 = 0.f;
    const uchar4* sb = S5 + (size_t)tc * 32768 + b * 4096;
    const float* wb = WFC + o * 4096;
    for (int i = 0; i < 64; ++i) {
        const int site = i * 64 + lane;
        const uchar4 s = sb[site];
        const float w = wb[site];
        a0 = fmaf(w, (float)s.x, a0);
        a1 = fmaf(w, (float)s.y, a1);
        a2 = fmaf(w, (float)s.z, a2);
        a3 = fmaf(w, (float)s.w, a3);
    }
#pragma unroll
    for (int m = 1; m < 64; m <<= 1) {
        a0 += __shfl_xor(a0, m, 64);
        a1 += __shfl_xor(a1, m, 64);
        a2 += __shfl_xor(a2, m, 64);
        a3 += __shfl_xor(a3, m, 64);
    }
    if (lane == 0)
        U6[(size_t)tc * 80 + b * 10 + o] = make_float4(a0, a1, a2, a3);
}

// final spike over 80 neurons; float4 chunks in, [n][t] fp32 out.
__global__ __launch_bounds__(128) void spike6_kernel(
    const float4* __restrict__ U6, float* __restrict__ Out, RefK rk)
{
    const int n = threadIdx.x;
    if (n >= 80) return;
    const float4* up = U6 + n;
    float* op = Out + (size_t)n * T_SAMPLE;
    float buf[10];
#pragma unroll
    for (int r = 0; r < 10; ++r) buf[r] = 0.f;

    float4 ring[8];
#pragma unroll
    for (int r = 0; r < 8; ++r) ring[r] = up[(size_t)r * 80];

#pragma unroll 8
    for (int ch = 0; ch < 72; ++ch) {
        const float4 cur = ring[ch & 7];
        const int pf = (ch + 8 < NCHUNK) ? ch + 8 : NCHUNK - 1;
        ring[ch & 7] = up[(size_t)pf * 80];
        float4 o;
        o.x = (float)spike_step(cur.x, buf, rk);
        o.y = (float)spike_step(cur.y, buf, rk);
        o.z = (float)spike_step(cur.z, buf, rk);
        o.w = (float)spike_step(cur.w, buf, rk);
        *(float4*)(op + ch * 4) = o;
    }
#pragma unroll
    for (int ch = 72; ch < NCHUNK; ++ch) {
        const float4 cur = ring[ch & 7];
        float4 o;
        o.x = (float)spike_step(cur.x, buf, rk);
        o.y = (float)spike_step(cur.y, buf, rk);
        o.z = (float)spike_step(cur.z, buf, rk);
        o.w = (float)spike_step(cur.w, buf, rk);
        *(float4*)(op + ch * 4) = o;
    }
}

extern "C" void kernel_launch(void* const* d_in, const int* in_sizes, int n_in,
                              void* d_out, int out_size, void* d_ws, size_t ws_size,
                              hipStream_t stream)
{
    const float* spikeIn = (const float*)d_in[0];  // [8,2,34,34,300]
    const float* w1 = (const float*)d_in[1];       // [16,2,5,5]
    const float* w2 = (const float*)d_in[2];       // [32,16,3,3]
    const float* w3 = (const float*)d_in[3];       // [64,32,3,3]
    const float* wfc = (const float*)d_in[4];      // [10,64,8,8]
    float* out = (float*)d_out;                    // [8,10,1,1,300]

    RefK rk;
    for (int t = 1; t <= 10; ++t)
        rk.v[t - 1] = (float)(-20.0 * (double)t * std::exp(1.0 - (double)t));

    // workspace tiers (U region first, then A, B, U6):
    //   huge: U 157.3 MB -> conv1 single launch (nbl1=8)
    //   big : U  78.6 MB -> conv1 x2, conv2 single
    //   small: U 39.3 MB -> conv1 x4, conv2 x2
    // A region (39.3 MB) now holds s5 / s2 / s4 (s1, s3 eliminated by fusion).
    // B region holds X only.
    const size_t A_BYTES = 39321600;
    const size_t B_BYTES = 9830400;
    const size_t U6_BYTES = 96000;
    const size_t U_HUGE = 157286400, U_BIG = 78643200, U_SMALL = 39321600;
    const size_t TAIL = A_BYTES + B_BYTES + U6_BYTES;
    const bool huge = ws_size >= U_HUGE + TAIL;
    const bool big = ws_size >= U_BIG + TAIL;
    const size_t U_BYTES = huge ? U_HUGE : (big ? U_BIG : U_SMALL);

    char* ws = (char*)d_ws;
    float4* U = (float4*)ws;
    char* Areg = ws + U_BYTES;
    uchar4* Bb = (uchar4*)(ws + U_BYTES + A_BYTES);
    float4* U6 = (float4*)(ws + U_BYTES + A_BYTES + B_BYTES);

    uchar4* X = Bb;                              // 5.55 MB, live through layer 1
    uchar4* s5 = (uchar4*)Areg;                  // 9.83 MB
    uchar4* s2 = (uchar4*)(Areg + 9830400);      // 9.83 MB, live layer1->conv2
    uchar4* s4 = (uchar4*)(Areg + 2 * 9830400);  // 4.92 MB, live layer2->conv3

    // ---- input transpose ----
    transpose_in_kernel<<<18496 / 16, 256, 0, stream>>>(spikeIn, (unsigned int*)X);

    // ---- layer 1: conv(2->16, k5) -> fused spike+pool2+spike -> s2 ----
    const int nbl1 = huge ? 8 : (big ? 4 : 2);
    for (int b0 = 0; b0 < 8; b0 += nbl1) {
        dim3 g1(NCHUNK, 16, nbl1);  // 16 tiles, OG=1, OPT=4
        conv_u_kernel<2, 16, 5, 32, 32, 34, 34, 4, 1>
            <<<g1, 256, 0, stream>>>(X, w1, U, b0, nbl1);
        spike_pool_spike_kernel<16, 32, 32>
            <<<(nbl1 * 4096) / 64, 64, 0, stream>>>(U, s2, nbl1, 32768, b0 * 4096, rk);
    }
    // ---- layer 2: conv(16->32, k3) -> fused spike+pool4+spike -> s4 ----
    const int nbl2 = (huge || big) ? 8 : 4;
    for (int b0 = 0; b0 < 8; b0 += nbl2) {
        dim3 g2(NCHUNK, 4, nbl2);   // 4 tiles, OG=1, OPT=8, c-split 2
        conv_u_kernel<16, 32, 3, 16, 16, 16, 16, 8, 2>
            <<<g2, 256, 0, stream>>>(s2, w2, U, b0, nbl2);
        spike_pool_spike_kernel<32, 16, 16>
            <<<(nbl2 * 2048) / 64, 64, 0, stream>>>(U, s4, nbl2, 16384, b0 * 2048, rk);
    }
    // ---- layer 3: conv(32->64, k3) + spike, full batch, c-split 2 ----
    {
        dim3 g3(NCHUNK, 2, 8);   // 1 tile, OG=2, OPT=8
        conv_u_kernel<32, 64, 3, 8, 8, 8, 8, 8, 2>
            <<<g3, 256, 0, stream>>>(s4, w3, U, 0, 8);
        spike_kernel<<<32768 / 64, 64, 0, stream>>>(U, s5, 32768, 32768, 0, rk);
    }
    // ---- dense + final spike ----
    dim3 g6(NCHUNK, 10, 8);
    dense_u_kernel<<<g6, 64, 0, stream>>>(s5, wfc, U6);
    spike6_kernel<<<1, 128, 0, stream>>>(U6, out, rk);
}

// Round 13
// 358.419 us; speedup vs baseline: 1.4743x; 1.4743x over previous
//
#include <hip/hip_runtime.h>
#include <cmath>

#define T_SAMPLE 300
#define NCHUNK 75   // T / 4

struct RefK { float v[10]; };

// One step of the SLAYER spike recurrence. buf[0..9] = pending refractory.
__device__ __forceinline__ unsigned char spike_step(float u, float* buf, const RefK& rk) {
    const float um = u + buf[0];
    const bool fire = um >= 10.0f;
    const float ev = fire ? 1.0f : 0.0f;
#pragma unroll
    for (int r = 0; r < 9; ++r) buf[r] = fmaf(ev, rk.v[r], buf[r + 1]);
    buf[9] = ev * rk.v[9];
    return fire ? (unsigned char)1 : (unsigned char)0;
}

// ---------------------------------------------------------------------------
// transpose input [B,2,34,34,T] f32 ({0,1}) -> X[tchunk][n][4] u8, n = b,c,y,x
// ---------------------------------------------------------------------------
__global__ __launch_bounds__(256) void transpose_in_k(
    const float* __restrict__ In, unsigned int* __restrict__ X)
{
    __shared__ unsigned int lds[16 * NCHUNK];
    const int blk = blockIdx.x;          // 1156 blocks x 16 neurons
    const int tn = threadIdx.x >> 4;     // 0..15 neuron
    const int tq = threadIdx.x & 15;     // 0..15 t-group
    const size_t n = (size_t)blk * 16 + tn;
#pragma unroll
    for (int p = 0; p < 5; ++p) {
        const int ch = p * 16 + tq;
        if (ch < NCHUNK) {
            const float4 v = *(const float4*)(In + n * T_SAMPLE + ch * 4);
            unsigned int u = (v.x != 0.f ? 1u : 0u) | (v.y != 0.f ? 0x100u : 0u) |
                             (v.z != 0.f ? 0x10000u : 0u) | (v.w != 0.f ? 0x1000000u : 0u);
            lds[tn * NCHUNK + ch] = u;
        }
    }
    __syncthreads();
    for (int idx = threadIdx.x; idx < 16 * NCHUNK; idx += 256) {
        const int ch = idx >> 4, t2 = idx & 15;
        X[(size_t)ch * 18496 + blk * 16 + t2] = lds[t2 * NCHUNK + ch];
    }
}

// ---------------------------------------------------------------------------
// conv body (R9 config - best measured): per-timestep 2D conv (pad=1), 4
// timesteps/thread, float4 LDS tile with padded row stride EWP=EW+1, CSPLIT
// ascending-c staging passes (FMA order preserved) to cap LDS footprint.
// Grid: x = tchunk, y = tile*OG+og, z = local batch (nbl runtime).
// ---------------------------------------------------------------------------
template <int IC, int OC, int K, int OH, int OW, int IH, int IW, int OPT, int CSPLIT>
__device__ __forceinline__ void conv_body(
    const uchar4* __restrict__ in_, const float* __restrict__ W,
    float4* __restrict__ U, int b0, int nbl)
{
    constexpr int TH = 8, TW = 8;
    constexpr int EH = TH + K - 1, EW = TW + K - 1;
    constexpr int EWP = EW + 1;          // padded row stride (odd)
    constexpr int NTX = OW / TW, NTY = OH / TH, NT = NTX * NTY;
    constexpr int KK = K * K;
    constexpr int ICH = IC / CSPLIT;
    constexpr int ES = ICH * EH * EW;    // staged elements per split
    constexpr int PLANE_IN = 8 * IC * IH * IW;   // full-batch chunk plane (uchar4)
    const int PLANE_U = nbl * OC * OH * OW;      // slice chunk plane (float4)

    __shared__ float4 tile[ICH * EH * EWP];

    const int tc = blockIdx.x;
    const int by = blockIdx.y;
    const int til = by % NT;
    const int og = by / NT;
    const int ty = til / NTX, tx = til % NTX;
    const int bl = blockIdx.z;
    const int b = b0 + bl;
    const int tid = threadIdx.x;
    const int wave = tid >> 6, lane = tid & 63;
    const int py = lane >> 3, px = lane & 7;

    const int iy0 = ty * TH - 1, ix0 = tx * TW - 1;  // PAD = 1
    const uchar4* ib = in_ + (size_t)tc * PLANE_IN + (size_t)b * IC * IH * IW;

    float acc[OPT][4];
#pragma unroll
    for (int j = 0; j < OPT; ++j)
#pragma unroll
        for (int k = 0; k < 4; ++k) acc[j][k] = 0.f;

    int ob = (og * 4 + wave) * OPT;
    ob = __builtin_amdgcn_readfirstlane(ob);   // wave-uniform -> scalar weight loads
    const float* Wp = W + (size_t)ob * IC * KK;

    for (int s = 0; s < CSPLIT; ++s) {
        if (s > 0) __syncthreads();          // prev split's reads done
        for (int e = tid; e < ES; e += 256) {
            const int cl = e / (EH * EW);
            const int r = e % (EH * EW);
            const int iy = r / EW, ix = r % EW;
            const int gy = iy0 + iy, gx = ix0 + ix;
            float4 v = make_float4(0.f, 0.f, 0.f, 0.f);
            if ((unsigned)gy < (unsigned)IH && (unsigned)gx < (unsigned)IW) {
                const uchar4 sv = ib[((s * ICH + cl) * IH + gy) * IW + gx];
                v = make_float4((float)sv.x, (float)sv.y, (float)sv.z, (float)sv.w);
            }
            tile[(cl * EH + iy) * EWP + ix] = v;
        }
        __syncthreads();

        for (int cl = 0; cl < ICH; ++cl) {
            const int c = s * ICH + cl;
#pragma unroll
            for (int dy = 0; dy < K; ++dy) {
                float wr[OPT][K];
#pragma unroll
                for (int j = 0; j < OPT; ++j)
#pragma unroll
                    for (int dx = 0; dx < K; ++dx)
                        wr[j][dx] = Wp[(j * IC + c) * KK + dy * K + dx];
#pragma unroll
                for (int dx = 0; dx < K; ++dx) {
                    const float4 v = tile[((cl * EH) + py + dy) * EWP + (px + dx)];
#pragma unroll
                    for (int j = 0; j < OPT; ++j) {
                        const float w = wr[j][dx];
                        acc[j][0] = fmaf(w, v.x, acc[j][0]);
                        acc[j][1] = fmaf(w, v.y, acc[j][1]);
                        acc[j][2] = fmaf(w, v.z, acc[j][2]);
                        acc[j][3] = fmaf(w, v.w, acc[j][3]);
                    }
                }
            }
        }
    }

    const int y = ty * TH + py, x = tx * TW + px;
#pragma unroll
    for (int j = 0; j < OPT; ++j) {
        const int nb = ((bl * OC + (ob + j)) * OH + y) * OW + x;
        U[(size_t)tc * PLANE_U + nb] = make_float4(acc[j][0], acc[j][1], acc[j][2], acc[j][3]);
    }
}

// distinct names per layer for per-dispatch profiling
__global__ __launch_bounds__(256) void conv1_k(
    const uchar4* __restrict__ in_, const float* __restrict__ W,
    float4* __restrict__ U, int b0, int nbl)
{ conv_body<2, 16, 5, 32, 32, 34, 34, 4, 1>(in_, W, U, b0, nbl); }

__global__ __launch_bounds__(256) void conv2_k(
    const uchar4* __restrict__ in_, const float* __restrict__ W,
    float4* __restrict__ U, int b0, int nbl)
{ conv_body<16, 32, 3, 16, 16, 16, 16, 8, 2>(in_, W, U, b0, nbl); }

__global__ __launch_bounds__(256) void conv3_k(
    const uchar4* __restrict__ in_, const float* __restrict__ W,
    float4* __restrict__ U, int b0, int nbl)
{ conv_body<32, 64, 3, 8, 8, 8, 8, 8, 2>(in_, W, U, b0, nbl); }

// ---------------------------------------------------------------------------
// spike body: per-neuron scan. float4 per chunk in, uchar4 per chunk out.
// Ring-8 prefetch; 64-thread blocks for max CU spread.
// ---------------------------------------------------------------------------
__device__ __forceinline__ void spike_body(
    const float4* __restrict__ U, uchar4* __restrict__ S,
    int nneur, int sstride, int soff, const RefK& rk)
{
    const int n = blockIdx.x * 64 + threadIdx.x;
    const float4* up = U + n;
    uchar4* sp = S + soff + n;
    float buf[10];
#pragma unroll
    for (int r = 0; r < 10; ++r) buf[r] = 0.f;

    float4 ring[8];
#pragma unroll
    for (int r = 0; r < 8; ++r) ring[r] = up[(size_t)r * nneur];

#pragma unroll 8
    for (int ch = 0; ch < 72; ++ch) {
        const float4 cur = ring[ch & 7];
        const int pf = (ch + 8 < NCHUNK) ? ch + 8 : NCHUNK - 1;
        ring[ch & 7] = up[(size_t)pf * nneur];
        uchar4 o;
        o.x = spike_step(cur.x, buf, rk);
        o.y = spike_step(cur.y, buf, rk);
        o.z = spike_step(cur.z, buf, rk);
        o.w = spike_step(cur.w, buf, rk);
        sp[(size_t)ch * sstride] = o;
    }
#pragma unroll
    for (int ch = 72; ch < NCHUNK; ++ch) {
        const float4 cur = ring[ch & 7];
        uchar4 o;
        o.x = spike_step(cur.x, buf, rk);
        o.y = spike_step(cur.y, buf, rk);
        o.z = spike_step(cur.z, buf, rk);
        o.w = spike_step(cur.w, buf, rk);
        sp[(size_t)ch * sstride] = o;
    }
}

__global__ __launch_bounds__(64) void spike1_k(
    const float4* U, uchar4* S, int nneur, int sstride, int soff, RefK rk)
{ spike_body(U, S, nneur, sstride, soff, rk); }

__global__ __launch_bounds__(64) void spike2_k(
    const float4* U, uchar4* S, int nneur, int sstride, int soff, RefK rk)
{ spike_body(U, S, nneur, sstride, soff, rk); }

__global__ __launch_bounds__(64) void spike3_k(
    const float4* U, uchar4* S, int nneur, int sstride, int soff, RefK rk)
{ spike_body(U, S, nneur, sstride, soff, rk); }

// ---------------------------------------------------------------------------
// pool(2)*11 + spike. Two 8-byte loads per chunk (x-pair rows). Ring-8.
// ---------------------------------------------------------------------------
__device__ __forceinline__ int bsum4(uint2 r0, uint2 r1, int k) {
    return (int)((r0.x >> (8 * k)) & 0xffu) + (int)((r0.y >> (8 * k)) & 0xffu)
         + (int)((r1.x >> (8 * k)) & 0xffu) + (int)((r1.y >> (8 * k)) & 0xffu);
}

template <int C, int H, int W>
__device__ __forceinline__ void pool_body(
    const uchar4* __restrict__ Sin, uchar4* __restrict__ Sout, const RefK& rk)
{
    constexpr int H2 = H / 2, W2 = W / 2;
    constexpr int SIN = 8 * C * H * W;     // chunk stride (uchar4 units)
    constexpr int SOUT = 8 * C * H2 * W2;
    const int n = blockIdx.x * 64 + threadIdx.x;   // exact multiple of 64
    const int x = n % W2;
    const int y = (n / W2) % H2;
    const int c = (n / (W2 * H2)) % C;
    const int b = n / (W2 * H2 * C);
    const int base = (((b * C + c) * H + 2 * y) * W + 2 * x);
    uchar4* q = Sout + n;

    float buf[10];
#pragma unroll
    for (int r = 0; r < 10; ++r) buf[r] = 0.f;

    uint2 r0[8], r1[8];
#pragma unroll
    for (int r = 0; r < 8; ++r) {
        r0[r] = *(const uint2*)(Sin + (size_t)r * SIN + base);
        r1[r] = *(const uint2*)(Sin + (size_t)r * SIN + base + W);
    }

#pragma unroll 8
    for (int ch = 0; ch < 72; ++ch) {
        const uint2 a0 = r0[ch & 7], a1 = r1[ch & 7];
        const int pf = (ch + 8 < NCHUNK) ? ch + 8 : NCHUNK - 1;
        r0[ch & 7] = *(const uint2*)(Sin + (size_t)pf * SIN + base);
        r1[ch & 7] = *(const uint2*)(Sin + (size_t)pf * SIN + base + W);
        uchar4 o;
        o.x = spike_step(11.0f * (float)bsum4(a0, a1, 0), buf, rk);
        o.y = spike_step(11.0f * (float)bsum4(a0, a1, 1), buf, rk);
        o.z = spike_step(11.0f * (float)bsum4(a0, a1, 2), buf, rk);
        o.w = spike_step(11.0f * (float)bsum4(a0, a1, 3), buf, rk);
        q[(size_t)ch * SOUT] = o;
    }
#pragma unroll
    for (int ch = 72; ch < NCHUNK; ++ch) {
        const uint2 a0 = r0[ch & 7], a1 = r1[ch & 7];
        uchar4 o;
        o.x = spike_step(11.0f * (float)bsum4(a0, a1, 0), buf, rk);
        o.y = spike_step(11.0f * (float)bsum4(a0, a1, 1), buf, rk);
        o.z = spike_step(11.0f * (float)bsum4(a0, a1, 2), buf, rk);
        o.w = spike_step(11.0f * (float)bsum4(a0, a1, 3), buf, rk);
        q[(size_t)ch * SOUT] = o;
    }
}

__global__ __launch_bounds__(64) void pool2_k(
    const uchar4* Sin, uchar4* Sout, RefK rk) { pool_body<16, 32, 32>(Sin, Sout, rk); }
__global__ __launch_bounds__(64) void pool4_k(
    const uchar4* Sin, uchar4* Sout, RefK rk) { pool_body<32, 16, 16>(Sin, Sout, rk); }

// ---------------------------------------------------------------------------
// dense u: U6[tc][b*10+o][4] = sum_site wfc[o,site] * s5[tc][b*4096+site][4]
// ---------------------------------------------------------------------------
__global__ __launch_bounds__(64) void dense_k(
    const uchar4* __restrict__ S5, const float* __restrict__ WFC,
    float4* __restrict__ U6)
{
    const int tc = blockIdx.x, o = blockIdx.y, b = blockIdx.z;
    const int lane = threadIdx.x;
    float a0 = 0.f, a1 = 0.f, a2 = 0.f, a3 = 0.f;
    const uchar4* sb = S5 + (size_t)tc * 32768 + b * 4096;
    const float* wb = WFC + o * 4096;
    for (int i = 0; i < 64; ++i) {
        const int site = i * 64 + lane;
        const uchar4 s = sb[site];
        const float w = wb[site];
        a0 = fmaf(w, (float)s.x, a0);
        a1 = fmaf(w, (float)s.y, a1);
        a2 = fmaf(w, (float)s.z, a2);
        a3 = fmaf(w, (float)s.w, a3);
    }
#pragma unroll
    for (int m = 1; m < 64; m <<= 1) {
        a0 += __shfl_xor(a0, m, 64);
        a1 += __shfl_xor(a1, m, 64);
        a2 += __shfl_xor(a2, m, 64);
        a3 += __shfl_xor(a3, m, 64);
    }
    if (lane == 0)
        U6[(size_t)tc * 80 + b * 10 + o] = make_float4(a0, a1, a2, a3);
}

// final spike over 80 neurons; float4 chunks in, [n][t] fp32 out.
__global__ __launch_bounds__(128) void spike6_k(
    const float4* __restrict__ U6, float* __restrict__ Out, RefK rk)
{
    const int n = threadIdx.x;
    if (n >= 80) return;
    const float4* up = U6 + n;
    float* op = Out + (size_t)n * T_SAMPLE;
    float buf[10];
#pragma unroll
    for (int r = 0; r < 10; ++r) buf[r] = 0.f;

    float4 ring[8];
#pragma unroll
    for (int r = 0; r < 8; ++r) ring[r] = up[(size_t)r * 80];

#pragma unroll 8
    for (int ch = 0; ch < 72; ++ch) {
        const float4 cur = ring[ch & 7];
        const int pf = (ch + 8 < NCHUNK) ? ch + 8 : NCHUNK - 1;
        ring[ch & 7] = up[(size_t)pf * 80];
        float4 o;
        o.x = (float)spike_step(cur.x, buf, rk);
        o.y = (float)spike_step(cur.y, buf, rk);
        o.z = (float)spike_step(cur.z, buf, rk);
        o.w = (float)spike_step(cur.w, buf, rk);
        *(float4*)(op + ch * 4) = o;
    }
#pragma unroll
    for (int ch = 72; ch < NCHUNK; ++ch) {
        const float4 cur = ring[ch & 7];
        float4 o;
        o.x = (float)spike_step(cur.x, buf, rk);
        o.y = (float)spike_step(cur.y, buf, rk);
        o.z = (float)spike_step(cur.z, buf, rk);
        o.w = (float)spike_step(cur.w, buf, rk);
        *(float4*)(op + ch * 4) = o;
    }
}

extern "C" void kernel_launch(void* const* d_in, const int* in_sizes, int n_in,
                              void* d_out, int out_size, void* d_ws, size_t ws_size,
                              hipStream_t stream)
{
    const float* spikeIn = (const float*)d_in[0];  // [8,2,34,34,300]
    const float* w1 = (const float*)d_in[1];       // [16,2,5,5]
    const float* w2 = (const float*)d_in[2];       // [32,16,3,3]
    const float* w3 = (const float*)d_in[3];       // [64,32,3,3]
    const float* wfc = (const float*)d_in[4];      // [10,64,8,8]
    float* out = (float*)d_out;                    // [8,10,1,1,300]

    RefK rk;
    for (int t = 1; t <= 10; ++t)
        rk.v[t - 1] = (float)(-20.0 * (double)t * std::exp(1.0 - (double)t));

    // workspace tiers (U region first, then A, B, U6):
    //   huge: U 157.3 MB -> conv1/spike1 single launches (nbl1=8)
    //   big : U  78.6 MB -> conv1 x2, conv2 single
    //   small: U 39.3 MB -> conv1 x4, conv2 x2
    const size_t A_BYTES = 39321600;
    const size_t B_BYTES = 9830400;
    const size_t U6_BYTES = 96000;
    const size_t U_HUGE = 157286400, U_BIG = 78643200, U_SMALL = 39321600;
    const size_t TAIL = A_BYTES + B_BYTES + U6_BYTES;
    const bool huge = ws_size >= U_HUGE + TAIL;
    const bool big = ws_size >= U_BIG + TAIL;
    const size_t U_BYTES = huge ? U_HUGE : (big ? U_BIG : U_SMALL);

    char* ws = (char*)d_ws;
    float4* U = (float4*)ws;
    uchar4* A = (uchar4*)(ws + U_BYTES);
    uchar4* Bb = (uchar4*)(ws + U_BYTES + A_BYTES);
    float4* U6 = (float4*)(ws + U_BYTES + A_BYTES + B_BYTES);

    uchar4* X = Bb;   // input transpose; dead after layer 1
    uchar4* s1 = A;
    uchar4* s2 = Bb;
    uchar4* s3 = A;   // s1 dead after pool2
    uchar4* s4 = Bb;  // s2 dead after conv2-u
    uchar4* s5 = A;   // s3 dead after pool4

    // ---- input transpose ----
    transpose_in_k<<<18496 / 16, 256, 0, stream>>>(spikeIn, (unsigned int*)X);

    // ---- layer 1: conv(2->16, k5) + spike ----
    const int nbl1 = huge ? 8 : (big ? 4 : 2);
    for (int b0 = 0; b0 < 8; b0 += nbl1) {
        dim3 g1(NCHUNK, 16, nbl1);  // 16 tiles, OG=1, OPT=4
        conv1_k<<<g1, 256, 0, stream>>>(X, w1, U, b0, nbl1);
        const int nn = nbl1 * 16384;
        spike1_k<<<nn / 64, 64, 0, stream>>>(U, s1, nn, 131072, b0 * 16384, rk);
    }
    // ---- pool2 + spike ----
    pool2_k<<<32768 / 64, 64, 0, stream>>>(s1, s2, rk);
    // ---- layer 2: conv(16->32, k3) + spike, c-split 2 ----
    const int nbl2 = (huge || big) ? 8 : 4;
    for (int b0 = 0; b0 < 8; b0 += nbl2) {
        dim3 g2(NCHUNK, 4, nbl2);   // 4 tiles, OG=1, OPT=8
        conv2_k<<<g2, 256, 0, stream>>>(s2, w2, U, b0, nbl2);
        const int nn = nbl2 * 8192;
        spike2_k<<<nn / 64, 64, 0, stream>>>(U, s3, nn, 65536, b0 * 8192, rk);
    }
    // ---- pool4 + spike ----
    pool4_k<<<16384 / 64, 64, 0, stream>>>(s3, s4, rk);
    // ---- layer 3: conv(32->64, k3) + spike, full batch, c-split 2 ----
    {
        dim3 g3(NCHUNK, 2, 8);   // 1 tile, OG=2, OPT=8
        conv3_k<<<g3, 256, 0, stream>>>(s4, w3, U, 0, 8);
        spike3_k<<<32768 / 64, 64, 0, stream>>>(U, s5, 32768, 32768, 0, rk);
    }
    // ---- dense + final spike ----
    dim3 g6(NCHUNK, 10, 8);
    dense_k<<<g6, 64, 0, stream>>>(s5, wfc, U6);
    spike6_k<<<1, 128, 0, stream>>>(U6, out, rk);
}

// Round 14
// 328.092 us; speedup vs baseline: 1.6106x; 1.0924x over previous
//
#include <hip/hip_runtime.h>
#include <hip/hip_bf16.h>
#include <cmath>

#define T_SAMPLE 300
#define NCHUNK 75   // T / 4

typedef __attribute__((ext_vector_type(8))) short short8;
typedef __attribute__((ext_vector_type(4))) float f32x4;

struct RefK { float v[10]; };

// One step of the SLAYER spike recurrence. buf[0..9] = pending refractory.
__device__ __forceinline__ unsigned char spike_step(float u, float* buf, const RefK& rk) {
    const float um = u + buf[0];
    const bool fire = um >= 10.0f;
    const float ev = fire ? 1.0f : 0.0f;
#pragma unroll
    for (int r = 0; r < 9; ++r) buf[r] = fmaf(ev, rk.v[r], buf[r + 1]);
    buf[9] = ev * rk.v[9];
    return fire ? (unsigned char)1 : (unsigned char)0;
}

// ---------------------------------------------------------------------------
// transpose input [B,2,34,34,T] f32 ({0,1}) -> X[tchunk][n][4] u8, n = b,c,y,x
// ---------------------------------------------------------------------------
__global__ __launch_bounds__(256) void transpose_in_k(
    const float* __restrict__ In, unsigned int* __restrict__ X)
{
    __shared__ unsigned int lds[16 * NCHUNK];
    const int blk = blockIdx.x;          // 1156 blocks x 16 neurons
    const int tn = threadIdx.x >> 4;     // 0..15 neuron
    const int tq = threadIdx.x & 15;     // 0..15 t-group
    const size_t n = (size_t)blk * 16 + tn;
#pragma unroll
    for (int p = 0; p < 5; ++p) {
        const int ch = p * 16 + tq;
        if (ch < NCHUNK) {
            const float4 v = *(const float4*)(In + n * T_SAMPLE + ch * 4);
            unsigned int u = (v.x != 0.f ? 1u : 0u) | (v.y != 0.f ? 0x100u : 0u) |
                             (v.z != 0.f ? 0x10000u : 0u) | (v.w != 0.f ? 0x1000000u : 0u);
            lds[tn * NCHUNK + ch] = u;
        }
    }
    __syncthreads();
    for (int idx = threadIdx.x; idx < 16 * NCHUNK; idx += 256) {
        const int ch = idx >> 4, t2 = idx & 15;
        X[(size_t)ch * 18496 + blk * 16 + t2] = lds[t2 * NCHUNK + ch];
    }
}

// ---------------------------------------------------------------------------
// conv body (fp32 path, R9/R13 config) for conv1/conv2.
// ---------------------------------------------------------------------------
template <int IC, int OC, int K, int OH, int OW, int IH, int IW, int OPT, int CSPLIT>
__device__ __forceinline__ void conv_body(
    const uchar4* __restrict__ in_, const float* __restrict__ W,
    float4* __restrict__ U, int b0, int nbl)
{
    constexpr int TH = 8, TW = 8;
    constexpr int EH = TH + K - 1, EW = TW + K - 1;
    constexpr int EWP = EW + 1;          // padded row stride (odd)
    constexpr int NTX = OW / TW, NTY = OH / TH, NT = NTX * NTY;
    constexpr int KK = K * K;
    constexpr int ICH = IC / CSPLIT;
    constexpr int ES = ICH * EH * EW;    // staged elements per split
    constexpr int PLANE_IN = 8 * IC * IH * IW;   // full-batch chunk plane (uchar4)
    const int PLANE_U = nbl * OC * OH * OW;      // slice chunk plane (float4)

    __shared__ float4 tile[ICH * EH * EWP];

    const int tc = blockIdx.x;
    const int by = blockIdx.y;
    const int til = by % NT;
    const int og = by / NT;
    const int ty = til / NTX, tx = til % NTX;
    const int bl = blockIdx.z;
    const int b = b0 + bl;
    const int tid = threadIdx.x;
    const int wave = tid >> 6, lane = tid & 63;
    const int py = lane >> 3, px = lane & 7;

    const int iy0 = ty * TH - 1, ix0 = tx * TW - 1;  // PAD = 1
    const uchar4* ib = in_ + (size_t)tc * PLANE_IN + (size_t)b * IC * IH * IW;

    float acc[OPT][4];
#pragma unroll
    for (int j = 0; j < OPT; ++j)
#pragma unroll
        for (int k = 0; k < 4; ++k) acc[j][k] = 0.f;

    int ob = (og * 4 + wave) * OPT;
    ob = __builtin_amdgcn_readfirstlane(ob);   // wave-uniform -> scalar weight loads
    const float* Wp = W + (size_t)ob * IC * KK;

    for (int s = 0; s < CSPLIT; ++s) {
        if (s > 0) __syncthreads();          // prev split's reads done
        for (int e = tid; e < ES; e += 256) {
            const int cl = e / (EH * EW);
            const int r = e % (EH * EW);
            const int iy = r / EW, ix = r % EW;
            const int gy = iy0 + iy, gx = ix0 + ix;
            float4 v = make_float4(0.f, 0.f, 0.f, 0.f);
            if ((unsigned)gy < (unsigned)IH && (unsigned)gx < (unsigned)IW) {
                const uchar4 sv = ib[((s * ICH + cl) * IH + gy) * IW + gx];
                v = make_float4((float)sv.x, (float)sv.y, (float)sv.z, (float)sv.w);
            }
            tile[(cl * EH + iy) * EWP + ix] = v;
        }
        __syncthreads();

        for (int cl = 0; cl < ICH; ++cl) {
            const int c = s * ICH + cl;
#pragma unroll
            for (int dy = 0; dy < K; ++dy) {
                float wr[OPT][K];
#pragma unroll
                for (int j = 0; j < OPT; ++j)
#pragma unroll
                    for (int dx = 0; dx < K; ++dx)
                        wr[j][dx] = Wp[(j * IC + c) * KK + dy * K + dx];
#pragma unroll
                for (int dx = 0; dx < K; ++dx) {
                    const float4 v = tile[((cl * EH) + py + dy) * EWP + (px + dx)];
#pragma unroll
                    for (int j = 0; j < OPT; ++j) {
                        const float w = wr[j][dx];
                        acc[j][0] = fmaf(w, v.x, acc[j][0]);
                        acc[j][1] = fmaf(w, v.y, acc[j][1]);
                        acc[j][2] = fmaf(w, v.z, acc[j][2]);
                        acc[j][3] = fmaf(w, v.w, acc[j][3]);
                    }
                }
            }
        }
    }

    const int y = ty * TH + py, x = tx * TW + px;
#pragma unroll
    for (int j = 0; j < OPT; ++j) {
        const int nb = ((bl * OC + (ob + j)) * OH + y) * OW + x;
        U[(size_t)tc * PLANE_U + nb] = make_float4(acc[j][0], acc[j][1], acc[j][2], acc[j][3]);
    }
}

__global__ __launch_bounds__(256) void conv1_k(
    const uchar4* __restrict__ in_, const float* __restrict__ W,
    float4* __restrict__ U, int b0, int nbl)
{ conv_body<2, 16, 5, 32, 32, 34, 34, 4, 1>(in_, W, U, b0, nbl); }

__global__ __launch_bounds__(256) void conv2_k(
    const uchar4* __restrict__ in_, const float* __restrict__ W,
    float4* __restrict__ U, int b0, int nbl)
{ conv_body<16, 32, 3, 16, 16, 16, 16, 8, 2>(in_, W, U, b0, nbl); }

// ---------------------------------------------------------------------------
// prep_w3: split w3 fp32 into 3 exact bf16 components (h,m,l) and store
// fragment-ordered for mfma_f32_16x16x32_bf16 A-operand (A[m=lane&15]
// [k=quad*8+j]). k-order = tap*32 + ic (one tap per K-step).
// Wr[(((s*9+ks)*4+mt)*64+lane)*8 + j] = split_s(w3[oc=mt*16+(lane&15)]
//                                               [ic=(lane>>4)*8+j][tap=ks])
// ---------------------------------------------------------------------------
__global__ __launch_bounds__(256) void prep_w3_k(
    const float* __restrict__ w3, unsigned short* __restrict__ Wr)
{
    const int g = blockIdx.x * 256 + threadIdx.x;   // 0..55295 (216 blocks exact)
    const int j = g & 7;
    const int lane = (g >> 3) & 63;
    const int mt = (g >> 9) & 3;
    const int rest = g >> 11;        // 0..26
    const int ks = rest % 9;
    const int s = rest / 9;
    const int oc = mt * 16 + (lane & 15);
    const int ic = (lane >> 4) * 8 + j;
    const float w = w3[(oc * 32 + ic) * 9 + ks];
    __hip_bfloat16 hb = __float2bfloat16(w);
    const float hf = __bfloat162float(hb);
    __hip_bfloat16 mb = __float2bfloat16(w - hf);
    const float mf = __bfloat162float(mb);
    __hip_bfloat16 lb = __float2bfloat16(w - hf - mf);   // exact 3-way split
    __hip_bfloat16 sel = (s == 0) ? hb : ((s == 1) ? mb : lb);
    Wr[g] = *(unsigned short*)&sel;
}

// ---------------------------------------------------------------------------
// conv3 via MFMA: per (tc, bl) block. LDS = zero-padded spike tile
// [4t][10][10][32ic] u8 (12.8 KB). Wave wv = pixel group (16 pixels).
// A = weights (M=oc, from Wr), B = spikes (N=pixel, ds_read_b64 + byte->bf16).
// D[m=oc][n=pixel]: col=lane&15 (pixel), row=quad*4+reg (oc) [m89-verified].
// 9 K-steps (taps) x 3 splits x 4 oc-tiles x 4 t = 432 MFMA/wave.
// ---------------------------------------------------------------------------
__global__ __launch_bounds__(256) void conv3_mfma_k(
    const unsigned int* __restrict__ s4u, const unsigned short* __restrict__ Wr,
    float4* __restrict__ U)
{
    __shared__ __align__(16) unsigned char pad[12800];   // [t][row10][col10][ic32]
    const int tc = blockIdx.x;
    const int bl = blockIdx.z;
    const int tid = threadIdx.x;
    const int wv = tid >> 6, lane = tid & 63;
    const int q = lane >> 4, n = lane & 15;

    // zero (borders must be 0)
    unsigned int* lp = (unsigned int*)pad;
    for (int i = tid; i < 3200; i += 256) lp[i] = 0u;
    __syncthreads();
    // fill interior: s4[tc][bl*32 + c][pix] u32 (4 t-bytes)
    const unsigned int* sb = s4u + (size_t)tc * 16384 + bl * 2048;
    for (int e = tid; e < 2048; e += 256) {
        const unsigned int v = sb[e];
        const int c = e >> 6, pix = e & 63;
        const int base = (((pix >> 3) + 1) * 10 + ((pix & 7) + 1)) * 32 + c;
        pad[base]        = (unsigned char)(v & 0xFFu);
        pad[3200 + base] = (unsigned char)((v >> 8) & 0xFFu);
        pad[6400 + base] = (unsigned char)((v >> 16) & 0xFFu);
        pad[9600 + base] = (unsigned char)(v >> 24);
    }
    __syncthreads();

    const int pixel = wv * 16 + n;
    const int py0 = pixel >> 3, px0 = pixel & 7;

    f32x4 acc[4][4];   // [oc-tile][t]
#pragma unroll
    for (int mt = 0; mt < 4; ++mt)
#pragma unroll
        for (int t = 0; t < 4; ++t) acc[mt][t] = (f32x4){0.f, 0.f, 0.f, 0.f};

    for (int ks = 0; ks < 9; ++ks) {
        const int dy = ks / 3, dx = ks % 3;
        short8 Af[12];
#pragma unroll
        for (int s = 0; s < 3; ++s)
#pragma unroll
            for (int mt = 0; mt < 4; ++mt)
                Af[s * 4 + mt] = *(const short8*)(Wr + ((((s * 9 + ks) * 4 + mt) * 64 + lane) * 8));
#pragma unroll
        for (int t = 0; t < 4; ++t) {
            const int off = ((t * 10 + py0 + dy) * 10 + (px0 + dx)) * 32 + q * 8;
            const uint2 w8 = *(const uint2*)(pad + off);   // 8 spike bytes (0/1)
            // byte -> bf16 (1.0 = 0x3F80), pack pairs
            union { uint4 u; short8 s8; } cv;
            cv.u.x = (w8.x & 0xFFu) * 0x3F80u | ((((w8.x >> 8) & 0xFFu) * 0x3F80u) << 16);
            cv.u.y = ((w8.x >> 16) & 0xFFu) * 0x3F80u | ((((w8.x >> 24) & 0xFFu) * 0x3F80u) << 16);
            cv.u.z = (w8.y & 0xFFu) * 0x3F80u | ((((w8.y >> 8) & 0xFFu) * 0x3F80u) << 16);
            cv.u.w = ((w8.y >> 16) & 0xFFu) * 0x3F80u | ((((w8.y >> 24) & 0xFFu) * 0x3F80u) << 16);
            const short8 Bf = cv.s8;
#pragma unroll
            for (int s = 0; s < 3; ++s)
#pragma unroll
                for (int mt = 0; mt < 4; ++mt)
                    acc[mt][t] = __builtin_amdgcn_mfma_f32_16x16x32_bf16(
                        Af[s * 4 + mt], Bf, acc[mt][t], 0, 0, 0);
        }
    }

    // store: oc = mt*16 + q*4 + r, pixel = wv*16 + n; float4 over t
    const size_t ub = (size_t)tc * 32768 + (size_t)bl * 4096;
#pragma unroll
    for (int mt = 0; mt < 4; ++mt)
#pragma unroll
        for (int r = 0; r < 4; ++r) {
            const int oc = mt * 16 + q * 4 + r;
            const int nb = oc * 64 + wv * 16 + n;
            U[ub + nb] = make_float4(acc[mt][0][r], acc[mt][1][r], acc[mt][2][r], acc[mt][3][r]);
        }
}

// ---------------------------------------------------------------------------
// spike body: per-neuron scan. float4 per chunk in, uchar4 per chunk out.
// ---------------------------------------------------------------------------
__device__ __forceinline__ void spike_body(
    const float4* __restrict__ U, uchar4* __restrict__ S,
    int nneur, int sstride, int soff, const RefK& rk)
{
    const int n = blockIdx.x * 64 + threadIdx.x;
    const float4* up = U + n;
    uchar4* sp = S + soff + n;
    float buf[10];
#pragma unroll
    for (int r = 0; r < 10; ++r) buf[r] = 0.f;

    float4 ring[8];
#pragma unroll
    for (int r = 0; r < 8; ++r) ring[r] = up[(size_t)r * nneur];

#pragma unroll 8
    for (int ch = 0; ch < 72; ++ch) {
        const float4 cur = ring[ch & 7];
        const int pf = (ch + 8 < NCHUNK) ? ch + 8 : NCHUNK - 1;
        ring[ch & 7] = up[(size_t)pf * nneur];
        uchar4 o;
        o.x = spike_step(cur.x, buf, rk);
        o.y = spike_step(cur.y, buf, rk);
        o.z = spike_step(cur.z, buf, rk);
        o.w = spike_step(cur.w, buf, rk);
        sp[(size_t)ch * sstride] = o;
    }
#pragma unroll
    for (int ch = 72; ch < NCHUNK; ++ch) {
        const float4 cur = ring[ch & 7];
        uchar4 o;
        o.x = spike_step(cur.x, buf, rk);
        o.y = spike_step(cur.y, buf, rk);
        o.z = spike_step(cur.z, buf, rk);
        o.w = spike_step(cur.w, buf, rk);
        sp[(size_t)ch * sstride] = o;
    }
}

__global__ __launch_bounds__(64) void spike1_k(
    const float4* U, uchar4* S, int nneur, int sstride, int soff, RefK rk)
{ spike_body(U, S, nneur, sstride, soff, rk); }

__global__ __launch_bounds__(64) void spike2_k(
    const float4* U, uchar4* S, int nneur, int sstride, int soff, RefK rk)
{ spike_body(U, S, nneur, sstride, soff, rk); }

__global__ __launch_bounds__(64) void spike3_k(
    const float4* U, uchar4* S, int nneur, int sstride, int soff, RefK rk)
{ spike_body(U, S, nneur, sstride, soff, rk); }

// ---------------------------------------------------------------------------
// pool(2)*11 + spike. Two 8-byte loads per chunk (x-pair rows). Ring-8.
// ---------------------------------------------------------------------------
__device__ __forceinline__ int bsum4(uint2 r0, uint2 r1, int k) {
    return (int)((r0.x >> (8 * k)) & 0xffu) + (int)((r0.y >> (8 * k)) & 0xffu)
         + (int)((r1.x >> (8 * k)) & 0xffu) + (int)((r1.y >> (8 * k)) & 0xffu);
}

template <int C, int H, int W>
__device__ __forceinline__ void pool_body(
    const uchar4* __restrict__ Sin, uchar4* __restrict__ Sout, const RefK& rk)
{
    constexpr int H2 = H / 2, W2 = W / 2;
    constexpr int SIN = 8 * C * H * W;     // chunk stride (uchar4 units)
    constexpr int SOUT = 8 * C * H2 * W2;
    const int n = blockIdx.x * 64 + threadIdx.x;   // exact multiple of 64
    const int x = n % W2;
    const int y = (n / W2) % H2;
    const int c = (n / (W2 * H2)) % C;
    const int b = n / (W2 * H2 * C);
    const int base = (((b * C + c) * H + 2 * y) * W + 2 * x);
    uchar4* q = Sout + n;

    float buf[10];
#pragma unroll
    for (int r = 0; r < 10; ++r) buf[r] = 0.f;

    uint2 r0[8], r1[8];
#pragma unroll
    for (int r = 0; r < 8; ++r) {
        r0[r] = *(const uint2*)(Sin + (size_t)r * SIN + base);
        r1[r] = *(const uint2*)(Sin + (size_t)r * SIN + base + W);
    }

#pragma unroll 8
    for (int ch = 0; ch < 72; ++ch) {
        const uint2 a0 = r0[ch & 7], a1 = r1[ch & 7];
        const int pf = (ch + 8 < NCHUNK) ? ch + 8 : NCHUNK - 1;
        r0[ch & 7] = *(const uint2*)(Sin + (size_t)pf * SIN + base);
        r1[ch & 7] = *(const uint2*)(Sin + (size_t)pf * SIN + base + W);
        uchar4 o;
        o.x = spike_step(11.0f * (float)bsum4(a0, a1, 0), buf, rk);
        o.y = spike_step(11.0f * (float)bsum4(a0, a1, 1), buf, rk);
        o.z = spike_step(11.0f * (float)bsum4(a0, a1, 2), buf, rk);
        o.w = spike_step(11.0f * (float)bsum4(a0, a1, 3), buf, rk);
        q[(size_t)ch * SOUT] = o;
    }
#pragma unroll
    for (int ch = 72; ch < NCHUNK; ++ch) {
        const uint2 a0 = r0[ch & 7], a1 = r1[ch & 7];
        uchar4 o;
        o.x = spike_step(11.0f * (float)bsum4(a0, a1, 0), buf, rk);
        o.y = spike_step(11.0f * (float)bsum4(a0, a1, 1), buf, rk);
        o.z = spike_step(11.0f * (float)bsum4(a0, a1, 2), buf, rk);
        o.w = spike_step(11.0f * (float)bsum4(a0, a1, 3), buf, rk);
        q[(size_t)ch * SOUT] = o;
    }
}

__global__ __launch_bounds__(64) void pool2_k(
    const uchar4* Sin, uchar4* Sout, RefK rk) { pool_body<16, 32, 32>(Sin, Sout, rk); }
__global__ __launch_bounds__(64) void pool4_k(
    const uchar4* Sin, uchar4* Sout, RefK rk) { pool_body<32, 16, 16>(Sin, Sout, rk); }

// ---------------------------------------------------------------------------
// dense u: U6[tc][b*10+o][4] = sum_site wfc[o,site] * s5[tc][b*4096+site][4]
// ---------------------------------------------------------------------------
__global__ __launch_bounds__(64) void dense_k(
    const uchar4* __restrict__ S5, const float* __restrict__ WFC,
    float4* __restrict__ U6)
{
    const int tc = blockIdx.x, o = blockIdx.y, b = blockIdx.z;
    const int lane = threadIdx.x;
    float a0 = 0.f, a1 = 0.f, a2 = 0.f, a3 = 0.f;
    const uchar4* sb = S5 + (size_t)tc * 32768 + b * 4096;
    const float* wb = WFC + o * 4096;
    for (int i = 0; i < 64; ++i) {
        const int site = i * 64 + lane;
        const uchar4 s = sb[site];
        const float w = wb[site];
        a0 = fmaf(w, (float)s.x, a0);
        a1 = fmaf(w, (float)s.y, a1);
        a2 = fmaf(w, (float)s.z, a2);
        a3 = fmaf(w, (float)s.w, a3);
    }
#pragma unroll
    for (int m = 1; m < 64; m <<= 1) {
        a0 += __shfl_xor(a0, m, 64);
        a1 += __shfl_xor(a1, m, 64);
        a2 += __shfl_xor(a2, m, 64);
        a3 += __shfl_xor(a3, m, 64);
    }
    if (lane == 0)
        U6[(size_t)tc * 80 + b * 10 + o] = make_float4(a0, a1, a2, a3);
}

// final spike over 80 neurons; float4 chunks in, [n][t] fp32 out.
__global__ __launch_bounds__(128) void spike6_k(
    const float4* __restrict__ U6, float* __restrict__ Out, RefK rk)
{
    const int n = threadIdx.x;
    if (n >= 80) return;
    const float4* up = U6 + n;
    float* op = Out + (size_t)n * T_SAMPLE;
    float buf[10];
#pragma unroll
    for (int r = 0; r < 10; ++r) buf[r] = 0.f;

    float4 ring[8];
#pragma unroll
    for (int r = 0; r < 8; ++r) ring[r] = up[(size_t)r * 80];

#pragma unroll 8
    for (int ch = 0; ch < 72; ++ch) {
        const float4 cur = ring[ch & 7];
        const int pf = (ch + 8 < NCHUNK) ? ch + 8 : NCHUNK - 1;
        ring[ch & 7] = up[(size_t)pf * 80];
        float4 o;
        o.x = (float)spike_step(cur.x, buf, rk);
        o.y = (float)spike_step(cur.y, buf, rk);
        o.z = (float)spike_step(cur.z, buf, rk);
        o.w = (float)spike_step(cur.w, buf, rk);
        *(float4*)(op + ch * 4) = o;
    }
#pragma unroll
    for (int ch = 72; ch < NCHUNK; ++ch) {
        const float4 cur = ring[ch & 7];
        float4 o;
        o.x = (float)spike_step(cur.x, buf, rk);
        o.y = (float)spike_step(cur.y, buf, rk);
        o.z = (float)spike_step(cur.z, buf, rk);
        o.w = (float)spike_step(cur.w, buf, rk);
        *(float4*)(op + ch * 4) = o;
    }
}

extern "C" void kernel_launch(void* const* d_in, const int* in_sizes, int n_in,
                              void* d_out, int out_size, void* d_ws, size_t ws_size,
                              hipStream_t stream)
{
    const float* spikeIn = (const float*)d_in[0];  // [8,2,34,34,300]
    const float* w1 = (const float*)d_in[1];       // [16,2,5,5]
    const float* w2 = (const float*)d_in[2];       // [32,16,3,3]
    const float* w3 = (const float*)d_in[3];       // [64,32,3,3]
    const float* wfc = (const float*)d_in[4];      // [10,64,8,8]
    float* out = (float*)d_out;                    // [8,10,1,1,300]

    RefK rk;
    for (int t = 1; t <= 10; ++t)
        rk.v[t - 1] = (float)(-20.0 * (double)t * std::exp(1.0 - (double)t));

    // workspace tiers (U region first, then A, B, U6):
    //   huge: U 157.3 MB -> conv1/spike1 single launches (nbl1=8)
    //   big : U  78.6 MB -> conv1 x2, conv2 single
    //   small: U 39.3 MB -> conv1 x4, conv2 x2
    // Wr (split conv3 weights, 0.22 MB) lives in the A region at +20 MB:
    // that range is free after pool2 (s1 dead; s3 ends at 19.66 MB).
    const size_t A_BYTES = 39321600;
    const size_t B_BYTES = 9830400;
    const size_t U6_BYTES = 96000;
    const size_t U_HUGE = 157286400, U_BIG = 78643200, U_SMALL = 39321600;
    const size_t TAIL = A_BYTES + B_BYTES + U6_BYTES;
    const bool huge = ws_size >= U_HUGE + TAIL;
    const bool big = ws_size >= U_BIG + TAIL;
    const size_t U_BYTES = huge ? U_HUGE : (big ? U_BIG : U_SMALL);

    char* ws = (char*)d_ws;
    float4* U = (float4*)ws;
    uchar4* A = (uchar4*)(ws + U_BYTES);
    uchar4* Bb = (uchar4*)(ws + U_BYTES + A_BYTES);
    float4* U6 = (float4*)(ws + U_BYTES + A_BYTES + B_BYTES);
    unsigned short* Wr = (unsigned short*)(ws + U_BYTES + 20971520);

    uchar4* X = Bb;   // input transpose; dead after layer 1
    uchar4* s1 = A;
    uchar4* s2 = Bb;
    uchar4* s3 = A;   // s1 dead after pool2
    uchar4* s4 = Bb;  // s2 dead after conv2-u
    uchar4* s5 = A;   // s3 dead after pool4

    // ---- input transpose ----
    transpose_in_k<<<18496 / 16, 256, 0, stream>>>(spikeIn, (unsigned int*)X);

    // ---- layer 1: conv(2->16, k5) + spike ----
    const int nbl1 = huge ? 8 : (big ? 4 : 2);
    for (int b0 = 0; b0 < 8; b0 += nbl1) {
        dim3 g1(NCHUNK, 16, nbl1);  // 16 tiles, OG=1, OPT=4
        conv1_k<<<g1, 256, 0, stream>>>(X, w1, U, b0, nbl1);
        const int nn = nbl1 * 16384;
        spike1_k<<<nn / 64, 64, 0, stream>>>(U, s1, nn, 131072, b0 * 16384, rk);
    }
    // ---- pool2 + spike ----
    pool2_k<<<32768 / 64, 64, 0, stream>>>(s1, s2, rk);
    // ---- conv3 weight split+reorder (A-region tail free from here) ----
    prep_w3_k<<<216, 256, 0, stream>>>(w3, Wr);
    // ---- layer 2: conv(16->32, k3) + spike, c-split 2 ----
    const int nbl2 = (huge || big) ? 8 : 4;
    for (int b0 = 0; b0 < 8; b0 += nbl2) {
        dim3 g2(NCHUNK, 4, nbl2);   // 4 tiles, OG=1, OPT=8
        conv2_k<<<g2, 256, 0, stream>>>(s2, w2, U, b0, nbl2);
        const int nn = nbl2 * 8192;
        spike2_k<<<nn / 64, 64, 0, stream>>>(U, s3, nn, 65536, b0 * 8192, rk);
    }
    // ---- pool4 + spike ----
    pool4_k<<<16384 / 64, 64, 0, stream>>>(s3, s4, rk);
    // ---- layer 3: MFMA conv(32->64, k3) + spike, full batch ----
    {
        dim3 g3(NCHUNK, 1, 8);   // (tc, -, bl): 600 blocks
        conv3_mfma_k<<<g3, 256, 0, stream>>>((const unsigned int*)s4, Wr, U);
        spike3_k<<<32768 / 64, 64, 0, stream>>>(U, s5, 32768, 32768, 0, rk);
    }
    // ---- dense + final spike ----
    dim3 g6(NCHUNK, 10, 8);
    dense_k<<<g6, 64, 0, stream>>>(s5, wfc, U6);
    spike6_k<<<1, 128, 0, stream>>>(U6, out, rk);
}

// Round 15
// 300.942 us; speedup vs baseline: 1.7559x; 1.0902x over previous
//
#include <hip/hip_runtime.h>
#include <hip/hip_bf16.h>
#include <cmath>

#define T_SAMPLE 300
#define NCHUNK 75   // T / 4

typedef __attribute__((ext_vector_type(8))) short short8;
typedef __attribute__((ext_vector_type(4))) float f32x4;

struct RefK { float v[10]; };

// One step of the SLAYER spike recurrence. buf[0..9] = pending refractory.
__device__ __forceinline__ unsigned char spike_step(float u, float* buf, const RefK& rk) {
    const float um = u + buf[0];
    const bool fire = um >= 10.0f;
    const float ev = fire ? 1.0f : 0.0f;
#pragma unroll
    for (int r = 0; r < 9; ++r) buf[r] = fmaf(ev, rk.v[r], buf[r + 1]);
    buf[9] = ev * rk.v[9];
    return fire ? (unsigned char)1 : (unsigned char)0;
}

// byte->bf16 pack: 8 spike bytes (0/1) -> short8 of bf16 (1.0 = 0x3F80)
__device__ __forceinline__ short8 bytes_to_bf16x8(uint2 w8) {
    union { uint4 u; short8 s8; } cv;
    cv.u.x = (w8.x & 0xFFu) * 0x3F80u | ((((w8.x >> 8) & 0xFFu) * 0x3F80u) << 16);
    cv.u.y = ((w8.x >> 16) & 0xFFu) * 0x3F80u | ((((w8.x >> 24) & 0xFFu) * 0x3F80u) << 16);
    cv.u.z = (w8.y & 0xFFu) * 0x3F80u | ((((w8.y >> 8) & 0xFFu) * 0x3F80u) << 16);
    cv.u.w = ((w8.y >> 16) & 0xFFu) * 0x3F80u | ((((w8.y >> 24) & 0xFFu) * 0x3F80u) << 16);
    return cv.s8;
}

// ---------------------------------------------------------------------------
// transpose input [B,2,34,34,T] f32 ({0,1}) -> X[tchunk][n][4] u8, n = b,c,y,x
// ---------------------------------------------------------------------------
__global__ __launch_bounds__(256) void transpose_in_k(
    const float* __restrict__ In, unsigned int* __restrict__ X)
{
    __shared__ unsigned int lds[16 * NCHUNK];
    const int blk = blockIdx.x;          // 1156 blocks x 16 neurons
    const int tn = threadIdx.x >> 4;     // 0..15 neuron
    const int tq = threadIdx.x & 15;     // 0..15 t-group
    const size_t n = (size_t)blk * 16 + tn;
#pragma unroll
    for (int p = 0; p < 5; ++p) {
        const int ch = p * 16 + tq;
        if (ch < NCHUNK) {
            const float4 v = *(const float4*)(In + n * T_SAMPLE + ch * 4);
            unsigned int u = (v.x != 0.f ? 1u : 0u) | (v.y != 0.f ? 0x100u : 0u) |
                             (v.z != 0.f ? 0x10000u : 0u) | (v.w != 0.f ? 0x1000000u : 0u);
            lds[tn * NCHUNK + ch] = u;
        }
    }
    __syncthreads();
    for (int idx = threadIdx.x; idx < 16 * NCHUNK; idx += 256) {
        const int ch = idx >> 4, t2 = idx & 15;
        X[(size_t)ch * 18496 + blk * 16 + t2] = lds[t2 * NCHUNK + ch];
    }
}

// ---------------------------------------------------------------------------
// conv body (fp32 path, R9/R13 config) for conv1.
// ---------------------------------------------------------------------------
template <int IC, int OC, int K, int OH, int OW, int IH, int IW, int OPT, int CSPLIT>
__device__ __forceinline__ void conv_body(
    const uchar4* __restrict__ in_, const float* __restrict__ W,
    float4* __restrict__ U, int b0, int nbl)
{
    constexpr int TH = 8, TW = 8;
    constexpr int EH = TH + K - 1, EW = TW + K - 1;
    constexpr int EWP = EW + 1;          // padded row stride (odd)
    constexpr int NTX = OW / TW, NTY = OH / TH, NT = NTX * NTY;
    constexpr int KK = K * K;
    constexpr int ICH = IC / CSPLIT;
    constexpr int ES = ICH * EH * EW;    // staged elements per split
    constexpr int PLANE_IN = 8 * IC * IH * IW;   // full-batch chunk plane (uchar4)
    const int PLANE_U = nbl * OC * OH * OW;      // slice chunk plane (float4)

    __shared__ float4 tile[ICH * EH * EWP];

    const int tc = blockIdx.x;
    const int by = blockIdx.y;
    const int til = by % NT;
    const int og = by / NT;
    const int ty = til / NTX, tx = til % NTX;
    const int bl = blockIdx.z;
    const int b = b0 + bl;
    const int tid = threadIdx.x;
    const int wave = tid >> 6, lane = tid & 63;
    const int py = lane >> 3, px = lane & 7;

    const int iy0 = ty * TH - 1, ix0 = tx * TW - 1;  // PAD = 1
    const uchar4* ib = in_ + (size_t)tc * PLANE_IN + (size_t)b * IC * IH * IW;

    float acc[OPT][4];
#pragma unroll
    for (int j = 0; j < OPT; ++j)
#pragma unroll
        for (int k = 0; k < 4; ++k) acc[j][k] = 0.f;

    int ob = (og * 4 + wave) * OPT;
    ob = __builtin_amdgcn_readfirstlane(ob);   // wave-uniform -> scalar weight loads
    const float* Wp = W + (size_t)ob * IC * KK;

    for (int s = 0; s < CSPLIT; ++s) {
        if (s > 0) __syncthreads();          // prev split's reads done
        for (int e = tid; e < ES; e += 256) {
            const int cl = e / (EH * EW);
            const int r = e % (EH * EW);
            const int iy = r / EW, ix = r % EW;
            const int gy = iy0 + iy, gx = ix0 + ix;
            float4 v = make_float4(0.f, 0.f, 0.f, 0.f);
            if ((unsigned)gy < (unsigned)IH && (unsigned)gx < (unsigned)IW) {
                const uchar4 sv = ib[((s * ICH + cl) * IH + gy) * IW + gx];
                v = make_float4((float)sv.x, (float)sv.y, (float)sv.z, (float)sv.w);
            }
            tile[(cl * EH + iy) * EWP + ix] = v;
        }
        __syncthreads();

        for (int cl = 0; cl < ICH; ++cl) {
            const int c = s * ICH + cl;
#pragma unroll
            for (int dy = 0; dy < K; ++dy) {
                float wr[OPT][K];
#pragma unroll
                for (int j = 0; j < OPT; ++j)
#pragma unroll
                    for (int dx = 0; dx < K; ++dx)
                        wr[j][dx] = Wp[(j * IC + c) * KK + dy * K + dx];
#pragma unroll
                for (int dx = 0; dx < K; ++dx) {
                    const float4 v = tile[((cl * EH) + py + dy) * EWP + (px + dx)];
#pragma unroll
                    for (int j = 0; j < OPT; ++j) {
                        const float w = wr[j][dx];
                        acc[j][0] = fmaf(w, v.x, acc[j][0]);
                        acc[j][1] = fmaf(w, v.y, acc[j][1]);
                        acc[j][2] = fmaf(w, v.z, acc[j][2]);
                        acc[j][3] = fmaf(w, v.w, acc[j][3]);
                    }
                }
            }
        }
    }

    const int y = ty * TH + py, x = tx * TW + px;
#pragma unroll
    for (int j = 0; j < OPT; ++j) {
        const int nb = ((bl * OC + (ob + j)) * OH + y) * OW + x;
        U[(size_t)tc * PLANE_U + nb] = make_float4(acc[j][0], acc[j][1], acc[j][2], acc[j][3]);
    }
}

__global__ __launch_bounds__(256) void conv1_k(
    const uchar4* __restrict__ in_, const float* __restrict__ W,
    float4* __restrict__ U, int b0, int nbl)
{ conv_body<2, 16, 5, 32, 32, 34, 34, 4, 1>(in_, W, U, b0, nbl); }

// ---------------------------------------------------------------------------
// prep_w3: split w3 fp32 into 3 exact bf16 components, A-fragment order.
// k-order = tap*32 + ic. Wr[(((s*9+ks)*4+mt)*64+lane)*8+j].
// ---------------------------------------------------------------------------
__global__ __launch_bounds__(256) void prep_w3_k(
    const float* __restrict__ w3, unsigned short* __restrict__ Wr)
{
    const int g = blockIdx.x * 256 + threadIdx.x;   // 0..55295 (216 blocks exact)
    const int j = g & 7;
    const int lane = (g >> 3) & 63;
    const int mt = (g >> 9) & 3;
    const int rest = g >> 11;        // 0..26
    const int ks = rest % 9;
    const int s = rest / 9;
    const int oc = mt * 16 + (lane & 15);
    const int ic = (lane >> 4) * 8 + j;
    const float w = w3[(oc * 32 + ic) * 9 + ks];
    __hip_bfloat16 hb = __float2bfloat16(w);
    const float hf = __bfloat162float(hb);
    __hip_bfloat16 mb = __float2bfloat16(w - hf);
    const float mf = __bfloat162float(mb);
    __hip_bfloat16 lb = __float2bfloat16(w - hf - mf);   // exact 3-way split
    __hip_bfloat16 sel = (s == 0) ? hb : ((s == 1) ? mb : lb);
    Wr[g] = *(unsigned short*)&sel;
}

// ---------------------------------------------------------------------------
// prep_w2: conv2 weights, tap-PAIR K-packing (k = tap_local*16 + ic, taps
// kp*2, kp*2+1; tap 9 padded with EXACT ZERO weights). 3 exact bf16 splits.
// Wr2[(((s*5+kp)*2+mt)*64+lane)*8+j]: oc=mt*16+(lane&15),
// tap=kp*2+(q>>1), ic=(q&1)*8+j, q=lane>>4.
// ---------------------------------------------------------------------------
__global__ __launch_bounds__(256) void prep_w2_k(
    const float* __restrict__ w2, unsigned short* __restrict__ Wr2)
{
    const int g = blockIdx.x * 256 + threadIdx.x;   // 0..15359 (60 blocks exact)
    const int j = g & 7;
    const int lane = (g >> 3) & 63;
    const int mt = (g >> 9) & 1;
    const int rest = g >> 10;        // 0..14
    const int kp = rest % 5;
    const int s = rest / 5;
    const int q = lane >> 4;
    const int oc = mt * 16 + (lane & 15);
    const int tap = kp * 2 + (q >> 1);
    const int ic = (q & 1) * 8 + j;
    const float w = (tap <= 8) ? w2[(oc * 16 + ic) * 9 + tap] : 0.f;
    __hip_bfloat16 hb = __float2bfloat16(w);
    const float hf = __bfloat162float(hb);
    __hip_bfloat16 mb = __float2bfloat16(w - hf);
    const float mf = __bfloat162float(mb);
    __hip_bfloat16 lb = __float2bfloat16(w - hf - mf);   // exact 3-way split
    __hip_bfloat16 sel = (s == 0) ? hb : ((s == 1) ? mb : lb);
    Wr2[g] = *(unsigned short*)&sel;
}

// ---------------------------------------------------------------------------
// conv2 via MFMA: per (tc, bl). LDS = zero-padded [4t][18][18][16ic] u8
// (20.7 KB). Wave wv handles pixel rows wv*4..wv*4+3 (N-tile = one row of 16
// cols). A = weights (M=oc, 2 tiles), B = spikes (ds_read_b64 + byte->bf16).
// K-step = tap pair (quads 0-1: tap 2kp, quads 2-3: tap 2kp+1; tap 9 has
// zero A-weights, B address clamped to tap 8). 480 MFMA/wave.
// ---------------------------------------------------------------------------
__global__ __launch_bounds__(256) void conv2_mfma_k(
    const unsigned int* __restrict__ s2u, const unsigned short* __restrict__ Wr2,
    float4* __restrict__ U, int b0, int nbl)
{
    __shared__ __align__(16) unsigned char pad[4 * 18 * 18 * 16];   // 20736
    const int tc = blockIdx.x;
    const int bl = blockIdx.z;
    const int b = b0 + bl;
    const int tid = threadIdx.x;
    const int wv = tid >> 6, lane = tid & 63;
    const int q = lane >> 4, n = lane & 15;
    const int PLANE_U = nbl * 8192;      // float4 per chunk

    // zero borders
    unsigned int* lp = (unsigned int*)pad;
    for (int i = tid; i < 5184; i += 256) lp[i] = 0u;
    __syncthreads();
    // fill interior: s2[tc][(b*16+c)*256 + pix] u32 (4 t-bytes)
    const unsigned int* sb = s2u + (size_t)tc * 32768 + b * 4096;
    for (int e = tid; e < 4096; e += 256) {
        const unsigned int v = sb[e];
        const int c = e >> 8, pix = e & 255;
        const int base = (((pix >> 4) + 1) * 18 + ((pix & 15) + 1)) * 16 + c;
        pad[base]         = (unsigned char)(v & 0xFFu);
        pad[5184 + base]  = (unsigned char)((v >> 8) & 0xFFu);
        pad[10368 + base] = (unsigned char)((v >> 16) & 0xFFu);
        pad[15552 + base] = (unsigned char)(v >> 24);
    }
    __syncthreads();

    for (int i = 0; i < 4; ++i) {
        const int r = wv * 4 + i;        // pixel row (N-tile)
        f32x4 acc[2][4];                 // [oc-tile][t]
#pragma unroll
        for (int mt = 0; mt < 2; ++mt)
#pragma unroll
            for (int t = 0; t < 4; ++t) acc[mt][t] = (f32x4){0.f, 0.f, 0.f, 0.f};

        for (int kp = 0; kp < 5; ++kp) {
            short8 Af[6];   // [s][mt]
#pragma unroll
            for (int s = 0; s < 3; ++s)
#pragma unroll
                for (int mt = 0; mt < 2; ++mt)
                    Af[s * 2 + mt] = *(const short8*)(Wr2 + ((((s * 5 + kp) * 2 + mt) * 64 + lane) * 8));
            int tap = kp * 2 + (q >> 1);
            if (tap > 8) tap = 8;        // pad step: A is zero, address just valid
            const int dy = tap / 3, dx = tap % 3;
#pragma unroll
            for (int t = 0; t < 4; ++t) {
                const int off = ((t * 18 + r + dy) * 18 + (n + dx)) * 16 + (q & 1) * 8;
                const short8 Bf = bytes_to_bf16x8(*(const uint2*)(pad + off));
#pragma unroll
                for (int s = 0; s < 3; ++s)
#pragma unroll
                    for (int mt = 0; mt < 2; ++mt)
                        acc[mt][t] = __builtin_amdgcn_mfma_f32_16x16x32_bf16(
                            Af[s * 2 + mt], Bf, acc[mt][t], 0, 0, 0);
            }
        }

        // D: col=lane&15 = pixel col n, row = q*4+reg = oc in tile
        const size_t ub = (size_t)tc * PLANE_U;
#pragma unroll
        for (int mt = 0; mt < 2; ++mt)
#pragma unroll
            for (int rr = 0; rr < 4; ++rr) {
                const int oc = mt * 16 + q * 4 + rr;
                const int nb = (bl * 32 + oc) * 256 + r * 16 + n;
                U[ub + nb] = make_float4(acc[mt][0][rr], acc[mt][1][rr], acc[mt][2][rr], acc[mt][3][rr]);
            }
    }
}

// ---------------------------------------------------------------------------
// conv3 via MFMA (R14, verified): [4t][10][10][32ic] u8 tile, k = tap*32+ic.
// ---------------------------------------------------------------------------
__global__ __launch_bounds__(256) void conv3_mfma_k(
    const unsigned int* __restrict__ s4u, const unsigned short* __restrict__ Wr,
    float4* __restrict__ U)
{
    __shared__ __align__(16) unsigned char pad[12800];   // [t][row10][col10][ic32]
    const int tc = blockIdx.x;
    const int bl = blockIdx.z;
    const int tid = threadIdx.x;
    const int wv = tid >> 6, lane = tid & 63;
    const int q = lane >> 4, n = lane & 15;

    unsigned int* lp = (unsigned int*)pad;
    for (int i = tid; i < 3200; i += 256) lp[i] = 0u;
    __syncthreads();
    const unsigned int* sb = s4u + (size_t)tc * 16384 + bl * 2048;
    for (int e = tid; e < 2048; e += 256) {
        const unsigned int v = sb[e];
        const int c = e >> 6, pix = e & 63;
        const int base = (((pix >> 3) + 1) * 10 + ((pix & 7) + 1)) * 32 + c;
        pad[base]        = (unsigned char)(v & 0xFFu);
        pad[3200 + base] = (unsigned char)((v >> 8) & 0xFFu);
        pad[6400 + base] = (unsigned char)((v >> 16) & 0xFFu);
        pad[9600 + base] = (unsigned char)(v >> 24);
    }
    __syncthreads();

    const int pixel = wv * 16 + n;
    const int py0 = pixel >> 3, px0 = pixel & 7;

    f32x4 acc[4][4];   // [oc-tile][t]
#pragma unroll
    for (int mt = 0; mt < 4; ++mt)
#pragma unroll
        for (int t = 0; t < 4; ++t) acc[mt][t] = (f32x4){0.f, 0.f, 0.f, 0.f};

    for (int ks = 0; ks < 9; ++ks) {
        const int dy = ks / 3, dx = ks % 3;
        short8 Af[12];
#pragma unroll
        for (int s = 0; s < 3; ++s)
#pragma unroll
            for (int mt = 0; mt < 4; ++mt)
                Af[s * 4 + mt] = *(const short8*)(Wr + ((((s * 9 + ks) * 4 + mt) * 64 + lane) * 8));
#pragma unroll
        for (int t = 0; t < 4; ++t) {
            const int off = ((t * 10 + py0 + dy) * 10 + (px0 + dx)) * 32 + q * 8;
            const short8 Bf = bytes_to_bf16x8(*(const uint2*)(pad + off));
#pragma unroll
            for (int s = 0; s < 3; ++s)
#pragma unroll
                for (int mt = 0; mt < 4; ++mt)
                    acc[mt][t] = __builtin_amdgcn_mfma_f32_16x16x32_bf16(
                        Af[s * 4 + mt], Bf, acc[mt][t], 0, 0, 0);
        }
    }

    const size_t ub = (size_t)tc * 32768 + (size_t)bl * 4096;
#pragma unroll
    for (int mt = 0; mt < 4; ++mt)
#pragma unroll
        for (int r = 0; r < 4; ++r) {
            const int oc = mt * 16 + q * 4 + r;
            const int nb = oc * 64 + wv * 16 + n;
            U[ub + nb] = make_float4(acc[mt][0][r], acc[mt][1][r], acc[mt][2][r], acc[mt][3][r]);
        }
}

// ---------------------------------------------------------------------------
// spike body: per-neuron scan. float4 per chunk in, uchar4 per chunk out.
// ---------------------------------------------------------------------------
__device__ __forceinline__ void spike_body(
    const float4* __restrict__ U, uchar4* __restrict__ S,
    int nneur, int sstride, int soff, const RefK& rk)
{
    const int n = blockIdx.x * 64 + threadIdx.x;
    const float4* up = U + n;
    uchar4* sp = S + soff + n;
    float buf[10];
#pragma unroll
    for (int r = 0; r < 10; ++r) buf[r] = 0.f;

    float4 ring[8];
#pragma unroll
    for (int r = 0; r < 8; ++r) ring[r] = up[(size_t)r * nneur];

#pragma unroll 8
    for (int ch = 0; ch < 72; ++ch) {
        const float4 cur = ring[ch & 7];
        const int pf = (ch + 8 < NCHUNK) ? ch + 8 : NCHUNK - 1;
        ring[ch & 7] = up[(size_t)pf * nneur];
        uchar4 o;
        o.x = spike_step(cur.x, buf, rk);
        o.y = spike_step(cur.y, buf, rk);
        o.z = spike_step(cur.z, buf, rk);
        o.w = spike_step(cur.w, buf, rk);
        sp[(size_t)ch * sstride] = o;
    }
#pragma unroll
    for (int ch = 72; ch < NCHUNK; ++ch) {
        const float4 cur = ring[ch & 7];
        uchar4 o;
        o.x = spike_step(cur.x, buf, rk);
        o.y = spike_step(cur.y, buf, rk);
        o.z = spike_step(cur.z, buf, rk);
        o.w = spike_step(cur.w, buf, rk);
        sp[(size_t)ch * sstride] = o;
    }
}

__global__ __launch_bounds__(64) void spike1_k(
    const float4* U, uchar4* S, int nneur, int sstride, int soff, RefK rk)
{ spike_body(U, S, nneur, sstride, soff, rk); }

__global__ __launch_bounds__(64) void spike2_k(
    const float4* U, uchar4* S, int nneur, int sstride, int soff, RefK rk)
{ spike_body(U, S, nneur, sstride, soff, rk); }

__global__ __launch_bounds__(64) void spike3_k(
    const float4* U, uchar4* S, int nneur, int sstride, int soff, RefK rk)
{ spike_body(U, S, nneur, sstride, soff, rk); }

// ---------------------------------------------------------------------------
// pool(2)*11 + spike. Two 8-byte loads per chunk (x-pair rows). Ring-8.
// ---------------------------------------------------------------------------
__device__ __forceinline__ int bsum4(uint2 r0, uint2 r1, int k) {
    return (int)((r0.x >> (8 * k)) & 0xffu) + (int)((r0.y >> (8 * k)) & 0xffu)
         + (int)((r1.x >> (8 * k)) & 0xffu) + (int)((r1.y >> (8 * k)) & 0xffu);
}

template <int C, int H, int W>
__device__ __forceinline__ void pool_body(
    const uchar4* __restrict__ Sin, uchar4* __restrict__ Sout, const RefK& rk)
{
    constexpr int H2 = H / 2, W2 = W / 2;
    constexpr int SIN = 8 * C * H * W;     // chunk stride (uchar4 units)
    constexpr int SOUT = 8 * C * H2 * W2;
    const int n = blockIdx.x * 64 + threadIdx.x;   // exact multiple of 64
    const int x = n % W2;
    const int y = (n / W2) % H2;
    const int c = (n / (W2 * H2)) % C;
    const int b = n / (W2 * H2 * C);
    const int base = (((b * C + c) * H + 2 * y) * W + 2 * x);
    uchar4* q = Sout + n;

    float buf[10];
#pragma unroll
    for (int r = 0; r < 10; ++r) buf[r] = 0.f;

    uint2 r0[8], r1[8];
#pragma unroll
    for (int r = 0; r < 8; ++r) {
        r0[r] = *(const uint2*)(Sin + (size_t)r * SIN + base);
        r1[r] = *(const uint2*)(Sin + (size_t)r * SIN + base + W);
    }

#pragma unroll 8
    for (int ch = 0; ch < 72; ++ch) {
        const uint2 a0 = r0[ch & 7], a1 = r1[ch & 7];
        const int pf = (ch + 8 < NCHUNK) ? ch + 8 : NCHUNK - 1;
        r0[ch & 7] = *(const uint2*)(Sin + (size_t)pf * SIN + base);
        r1[ch & 7] = *(const uint2*)(Sin + (size_t)pf * SIN + base + W);
        uchar4 o;
        o.x = spike_step(11.0f * (float)bsum4(a0, a1, 0), buf, rk);
        o.y = spike_step(11.0f * (float)bsum4(a0, a1, 1), buf, rk);
        o.z = spike_step(11.0f * (float)bsum4(a0, a1, 2), buf, rk);
        o.w = spike_step(11.0f * (float)bsum4(a0, a1, 3), buf, rk);
        q[(size_t)ch * SOUT] = o;
    }
#pragma unroll
    for (int ch = 72; ch < NCHUNK; ++ch) {
        const uint2 a0 = r0[ch & 7], a1 = r1[ch & 7];
        uchar4 o;
        o.x = spike_step(11.0f * (float)bsum4(a0, a1, 0), buf, rk);
        o.y = spike_step(11.0f * (float)bsum4(a0, a1, 1), buf, rk);
        o.z = spike_step(11.0f * (float)bsum4(a0, a1, 2), buf, rk);
        o.w = spike_step(11.0f * (float)bsum4(a0, a1, 3), buf, rk);
        q[(size_t)ch * SOUT] = o;
    }
}

__global__ __launch_bounds__(64) void pool2_k(
    const uchar4* Sin, uchar4* Sout, RefK rk) { pool_body<16, 32, 32>(Sin, Sout, rk); }
__global__ __launch_bounds__(64) void pool4_k(
    const uchar4* Sin, uchar4* Sout, RefK rk) { pool_body<32, 16, 16>(Sin, Sout, rk); }

// ---------------------------------------------------------------------------
// dense u: U6[tc][b*10+o][4] = sum_site wfc[o,site] * s5[tc][b*4096+site][4]
// ---------------------------------------------------------------------------
__global__ __launch_bounds__(64) void dense_k(
    const uchar4* __restrict__ S5, const float* __restrict__ WFC,
    float4* __restrict__ U6)
{
    const int tc = blockIdx.x, o = blockIdx.y, b = blockIdx.z;
    const int lane = threadIdx.x;
    float a0 = 0.f, a1 = 0.f, a2 = 0.f, a3 = 0.f;
    const uchar4* sb = S5 + (size_t)tc * 32768 + b * 4096;
    const float* wb = WFC + o * 4096;
    for (int i = 0; i < 64; ++i) {
        const int site = i * 64 + lane;
        const uchar4 s = sb[site];
        const float w = wb[site];
        a0 = fmaf(w, (float)s.x, a0);
        a1 = fmaf(w, (float)s.y, a1);
        a2 = fmaf(w, (float)s.z, a2);
        a3 = fmaf(w, (float)s.w, a3);
    }
#pragma unroll
    for (int m = 1; m < 64; m <<= 1) {
        a0 += __shfl_xor(a0, m, 64);
        a1 += __shfl_xor(a1, m, 64);
        a2 += __shfl_xor(a2, m, 64);
        a3 += __shfl_xor(a3, m, 64);
    }
    if (lane == 0)
        U6[(size_t)tc * 80 + b * 10 + o] = make_float4(a0, a1, a2, a3);
}

// final spike over 80 neurons; float4 chunks in, [n][t] fp32 out.
__global__ __launch_bounds__(128) void spike6_k(
    const float4* __restrict__ U6, float* __restrict__ Out, RefK rk)
{
    const int n = threadIdx.x;
    if (n >= 80) return;
    const float4* up = U6 + n;
    float* op = Out + (size_t)n * T_SAMPLE;
    float buf[10];
#pragma unroll
    for (int r = 0; r < 10; ++r) buf[r] = 0.f;

    float4 ring[8];
#pragma unroll
    for (int r = 0; r < 8; ++r) ring[r] = up[(size_t)r * 80];

#pragma unroll 8
    for (int ch = 0; ch < 72; ++ch) {
        const float4 cur = ring[ch & 7];
        const int pf = (ch + 8 < NCHUNK) ? ch + 8 : NCHUNK - 1;
        ring[ch & 7] = up[(size_t)pf * 80];
        float4 o;
        o.x = (float)spike_step(cur.x, buf, rk);
        o.y = (float)spike_step(cur.y, buf, rk);
        o.z = (float)spike_step(cur.z, buf, rk);
        o.w = (float)spike_step(cur.w, buf, rk);
        *(float4*)(op + ch * 4) = o;
    }
#pragma unroll
    for (int ch = 72; ch < NCHUNK; ++ch) {
        const float4 cur = ring[ch & 7];
        float4 o;
        o.x = (float)spike_step(cur.x, buf, rk);
        o.y = (float)spike_step(cur.y, buf, rk);
        o.z = (float)spike_step(cur.z, buf, rk);
        o.w = (float)spike_step(cur.w, buf, rk);
        *(float4*)(op + ch * 4) = o;
    }
}

extern "C" void kernel_launch(void* const* d_in, const int* in_sizes, int n_in,
                              void* d_out, int out_size, void* d_ws, size_t ws_size,
                              hipStream_t stream)
{
    const float* spikeIn = (const float*)d_in[0];  // [8,2,34,34,300]
    const float* w1 = (const float*)d_in[1];       // [16,2,5,5]
    const float* w2 = (const float*)d_in[2];       // [32,16,3,3]
    const float* w3 = (const float*)d_in[3];       // [64,32,3,3]
    const float* wfc = (const float*)d_in[4];      // [10,64,8,8]
    float* out = (float*)d_out;                    // [8,10,1,1,300]

    RefK rk;
    for (int t = 1; t <= 10; ++t)
        rk.v[t - 1] = (float)(-20.0 * (double)t * std::exp(1.0 - (double)t));

    // workspace tiers (U region first, then A, B, U6):
    //   huge: U 157.3 MB -> conv1/spike1 single launches (nbl1=8)
    //   big : U  78.6 MB -> conv1 x2, conv2 single
    //   small: U 39.3 MB -> conv1 x4, conv2 x2
    // Wr (conv3, 110.6 KB) at A+20 MB; Wr2 (conv2, 30.7 KB) at A+20 MB+128K.
    // That range is free after pool2 (s1 dead; s3 ends at 19.66 MB).
    const size_t A_BYTES = 39321600;
    const size_t B_BYTES = 9830400;
    const size_t U6_BYTES = 96000;
    const size_t U_HUGE = 157286400, U_BIG = 78643200, U_SMALL = 39321600;
    const size_t TAIL = A_BYTES + B_BYTES + U6_BYTES;
    const bool huge = ws_size >= U_HUGE + TAIL;
    const bool big = ws_size >= U_BIG + TAIL;
    const size_t U_BYTES = huge ? U_HUGE : (big ? U_BIG : U_SMALL);

    char* ws = (char*)d_ws;
    float4* U = (float4*)ws;
    uchar4* A = (uchar4*)(ws + U_BYTES);
    uchar4* Bb = (uchar4*)(ws + U_BYTES + A_BYTES);
    float4* U6 = (float4*)(ws + U_BYTES + A_BYTES + B_BYTES);
    unsigned short* Wr = (unsigned short*)(ws + U_BYTES + 20971520);
    unsigned short* Wr2 = (unsigned short*)(ws + U_BYTES + 20971520 + 131072);

    uchar4* X = Bb;   // input transpose; dead after layer 1
    uchar4* s1 = A;
    uchar4* s2 = Bb;
    uchar4* s3 = A;   // s1 dead after pool2
    uchar4* s4 = Bb;  // s2 dead after conv2-u
    uchar4* s5 = A;   // s3 dead after pool4

    // ---- input transpose ----
    transpose_in_k<<<18496 / 16, 256, 0, stream>>>(spikeIn, (unsigned int*)X);

    // ---- layer 1: conv(2->16, k5) + spike ----
    const int nbl1 = huge ? 8 : (big ? 4 : 2);
    for (int b0 = 0; b0 < 8; b0 += nbl1) {
        dim3 g1(NCHUNK, 16, nbl1);  // 16 tiles, OG=1, OPT=4
        conv1_k<<<g1, 256, 0, stream>>>(X, w1, U, b0, nbl1);
        const int nn = nbl1 * 16384;
        spike1_k<<<nn / 64, 64, 0, stream>>>(U, s1, nn, 131072, b0 * 16384, rk);
    }
    // ---- pool2 + spike ----
    pool2_k<<<32768 / 64, 64, 0, stream>>>(s1, s2, rk);
    // ---- weight split+reorder (A-region tail free from here) ----
    prep_w2_k<<<60, 256, 0, stream>>>(w2, Wr2);
    prep_w3_k<<<216, 256, 0, stream>>>(w3, Wr);
    // ---- layer 2: MFMA conv(16->32, k3) + spike ----
    const int nbl2 = (huge || big) ? 8 : 4;
    for (int b0 = 0; b0 < 8; b0 += nbl2) {
        dim3 g2(NCHUNK, 1, nbl2);
        conv2_mfma_k<<<g2, 256, 0, stream>>>((const unsigned int*)s2, Wr2, U, b0, nbl2);
        const int nn = nbl2 * 8192;
        spike2_k<<<nn / 64, 64, 0, stream>>>(U, s3, nn, 65536, b0 * 8192, rk);
    }
    // ---- pool4 + spike ----
    pool4_k<<<16384 / 64, 64, 0, stream>>>(s3, s4, rk);
    // ---- layer 3: MFMA conv(32->64, k3) + spike, full batch ----
    {
        dim3 g3(NCHUNK, 1, 8);   // (tc, -, bl): 600 blocks
        conv3_mfma_k<<<g3, 256, 0, stream>>>((const unsigned int*)s4, Wr, U);
        spike3_k<<<32768 / 64, 64, 0, stream>>>(U, s5, 32768, 32768, 0, rk);
    }
    // ---- dense + final spike ----
    dim3 g6(NCHUNK, 10, 8);
    dense_k<<<g6, 64, 0, stream>>>(s5, wfc, U6);
    spike6_k<<<1, 128, 0, stream>>>(U6, out, rk);
}

// Round 17
// 287.652 us; speedup vs baseline: 1.8370x; 1.0462x over previous
//
#include <hip/hip_runtime.h>
#include <hip/hip_bf16.h>
#include <cmath>

#define T_SAMPLE 300
#define NCHUNK 75   // T / 4

typedef __attribute__((ext_vector_type(8))) short short8;
typedef __attribute__((ext_vector_type(4))) float f32x4;

struct RefK { float v[10]; };

// One step of the SLAYER spike recurrence. buf[0..9] = pending refractory.
__device__ __forceinline__ unsigned char spike_step(float u, float* buf, const RefK& rk) {
    const float um = u + buf[0];
    const bool fire = um >= 10.0f;
    const float ev = fire ? 1.0f : 0.0f;
#pragma unroll
    for (int r = 0; r < 9; ++r) buf[r] = fmaf(ev, rk.v[r], buf[r + 1]);
    buf[9] = ev * rk.v[9];
    return fire ? (unsigned char)1 : (unsigned char)0;
}

// byte->bf16 pack: 8 spike bytes (0/1) -> short8 of bf16 (1.0 = 0x3F80)
__device__ __forceinline__ short8 bytes_to_bf16x8(uint2 w8) {
    union { uint4 u; short8 s8; } cv;
    cv.u.x = (w8.x & 0xFFu) * 0x3F80u | ((((w8.x >> 8) & 0xFFu) * 0x3F80u) << 16);
    cv.u.y = ((w8.x >> 16) & 0xFFu) * 0x3F80u | ((((w8.x >> 24) & 0xFFu) * 0x3F80u) << 16);
    cv.u.z = (w8.y & 0xFFu) * 0x3F80u | ((((w8.y >> 8) & 0xFFu) * 0x3F80u) << 16);
    cv.u.w = ((w8.y >> 16) & 0xFFu) * 0x3F80u | ((((w8.y >> 24) & 0xFFu) * 0x3F80u) << 16);
    return cv.s8;
}

// 3-way exact bf16 split selector (24 mantissa bits = 3x8; residual 0)
__device__ __forceinline__ unsigned short bf16_split_sel(float w, int s) {
    __hip_bfloat16 hb = __float2bfloat16(w);
    const float hf = __bfloat162float(hb);
    __hip_bfloat16 mb = __float2bfloat16(w - hf);
    const float mf = __bfloat162float(mb);
    __hip_bfloat16 lb = __float2bfloat16(w - hf - mf);
    __hip_bfloat16 sel = (s == 0) ? hb : ((s == 1) ? mb : lb);
    return *(unsigned short*)&sel;
}

// ---------------------------------------------------------------------------
// transpose input [B,2,34,34,T] f32 ({0,1}) -> X[tchunk][n][4] u8, n = b,c,y,x
// ---------------------------------------------------------------------------
__global__ __launch_bounds__(256) void transpose_in_k(
    const float* __restrict__ In, unsigned int* __restrict__ X)
{
    __shared__ unsigned int lds[16 * NCHUNK];
    const int blk = blockIdx.x;          // 1156 blocks x 16 neurons
    const int tn = threadIdx.x >> 4;     // 0..15 neuron
    const int tq = threadIdx.x & 15;     // 0..15 t-group
    const size_t n = (size_t)blk * 16 + tn;
#pragma unroll
    for (int p = 0; p < 5; ++p) {
        const int ch = p * 16 + tq;
        if (ch < NCHUNK) {
            const float4 v = *(const float4*)(In + n * T_SAMPLE + ch * 4);
            unsigned int u = (v.x != 0.f ? 1u : 0u) | (v.y != 0.f ? 0x100u : 0u) |
                             (v.z != 0.f ? 0x10000u : 0u) | (v.w != 0.f ? 0x1000000u : 0u);
            lds[tn * NCHUNK + ch] = u;
        }
    }
    __syncthreads();
    for (int idx = threadIdx.x; idx < 16 * NCHUNK; idx += 256) {
        const int ch = idx >> 4, t2 = idx & 15;
        X[(size_t)ch * 18496 + blk * 16 + t2] = lds[t2 * NCHUNK + ch];
    }
}

// ---------------------------------------------------------------------------
// prep_w1: conv1 weights for MFMA, c-DUPLICATED packing. k = slot*4 + c2,
// slot = dy*6+dx (dx=5 and slot>=30 zero), c = c2&1, weight = w/2 (dup x2).
// Wr1[((s*4+ks)*64+lane)*8+j]: oc = lane&15, k = ks*32 + (lane>>4)*8 + j.
// ---------------------------------------------------------------------------
__global__ __launch_bounds__(256) void prep_w1_k(
    const float* __restrict__ w1, unsigned short* __restrict__ Wr1)
{
    const int g = blockIdx.x * 256 + threadIdx.x;   // 0..6143 (24 blocks exact)
    const int j = g & 7;
    const int lane = (g >> 3) & 63;
    const int ks = (g >> 9) & 3;
    const int s = g >> 11;               // 0..2
    const int q = lane >> 4;
    const int oc = lane & 15;
    const int kg = ks * 32 + q * 8 + j;
    const int slot = kg >> 2, c = kg & 1;
    const int dy = slot / 6, dx = slot % 6;
    const float w = (dy < 5 && dx < 5) ? w1[((oc * 2 + c) * 5 + dy) * 5 + dx] * 0.5f : 0.f;
    Wr1[g] = bf16_split_sel(w, s);
}

// ---------------------------------------------------------------------------
// prep_w3: conv3 weights, k = tap*32 + ic. Wr[(((s*9+ks)*4+mt)*64+lane)*8+j].
// ---------------------------------------------------------------------------
__global__ __launch_bounds__(256) void prep_w3_k(
    const float* __restrict__ w3, unsigned short* __restrict__ Wr)
{
    const int g = blockIdx.x * 256 + threadIdx.x;   // 0..55295 (216 blocks exact)
    const int j = g & 7;
    const int lane = (g >> 3) & 63;
    const int mt = (g >> 9) & 3;
    const int rest = g >> 11;        // 0..26
    const int ks = rest % 9;
    const int s = rest / 9;
    const int oc = mt * 16 + (lane & 15);
    const int ic = (lane >> 4) * 8 + j;
    Wr[g] = bf16_split_sel(w3[(oc * 32 + ic) * 9 + ks], s);
}

// ---------------------------------------------------------------------------
// prep_w2: conv2 weights, tap-pair packing (k = tap_local*16 + ic; tap 9
// padded with exact zeros). Wr2[(((s*5+kp)*2+mt)*64+lane)*8+j].
// ---------------------------------------------------------------------------
__global__ __launch_bounds__(256) void prep_w2_k(
    const float* __restrict__ w2, unsigned short* __restrict__ Wr2)
{
    const int g = blockIdx.x * 256 + threadIdx.x;   // 0..15359 (60 blocks exact)
    const int j = g & 7;
    const int lane = (g >> 3) & 63;
    const int mt = (g >> 9) & 1;
    const int rest = g >> 10;        // 0..14
    const int kp = rest % 5;
    const int s = rest / 5;
    const int q = lane >> 4;
    const int oc = mt * 16 + (lane & 15);
    const int tap = kp * 2 + (q >> 1);
    const int ic = (q & 1) * 8 + j;
    const float w = (tap <= 8) ? w2[(oc * 16 + ic) * 9 + tap] : 0.f;
    Wr2[g] = bf16_split_sel(w, s);
}

// ---------------------------------------------------------------------------
// conv1 via MFMA: per (tc, tile, bl). LDS = zero-padded [4t][12r][16col][4]
// u8 (3 KB), inner dim = [c0,c1,c0,c1] duplicate. Wave = 16 pixels, M = all
// 16 oc. 4 K-steps x 3 splits x 4t = 48 MFMA/wave. B-frag = 2x ds_read_b32.
// ---------------------------------------------------------------------------
__global__ __launch_bounds__(256) void conv1_mfma_k(
    const unsigned int* __restrict__ Xu, const unsigned short* __restrict__ Wr1,
    float4* __restrict__ U, int b0, int nbl)
{
    __shared__ __align__(16) unsigned int pad[768];   // [t4][r12][col16] u32-dup
    const int tc = blockIdx.x;
    const int tile = blockIdx.y;           // 16 tiles of 8x8
    const int ty = tile >> 2, tx = tile & 3;
    const int bl = blockIdx.z;
    const int b = b0 + bl;
    const int tid = threadIdx.x;
    const int wv = tid >> 6, lane = tid & 63;
    const int q = lane >> 4, n = lane & 15;
    const int PLANE_U = nbl * 16384;

    for (int i = tid; i < 768; i += 256) pad[i] = 0u;
    __syncthreads();
    const unsigned int* xb = Xu + (size_t)tc * 18496;
    if (tid < 192) {
        const int r = tid >> 4, col = tid & 15;
        const int y = ty * 8 + r - 1, x = tx * 8 + col - 1;
        unsigned int w0 = 0u, w1v = 0u;
        if ((unsigned)y < 34u && (unsigned)x < 34u) {
            w0 = xb[((b * 2 + 0) * 34 + y) * 34 + x];
            w1v = xb[((b * 2 + 1) * 34 + y) * 34 + x];
        }
#pragma unroll
        for (int t = 0; t < 4; ++t) {
            const unsigned int b0b = (w0 >> (8 * t)) & 0xFFu;
            const unsigned int b1b = (w1v >> (8 * t)) & 0xFFu;
            pad[(t * 12 + r) * 16 + col] = b0b | (b1b << 8) | (b0b << 16) | (b1b << 24);
        }
    }
    __syncthreads();

    const int pixel = wv * 16 + n;
    const int py0 = pixel >> 3, px0 = pixel & 7;

    short8 Af[12];   // [s][ks]
#pragma unroll
    for (int s = 0; s < 3; ++s)
#pragma unroll
        for (int ks = 0; ks < 4; ++ks)
            Af[s * 4 + ks] = *(const short8*)(Wr1 + (((s * 4 + ks) * 64 + lane) * 8));

    f32x4 acc[4];
#pragma unroll
    for (int t = 0; t < 4; ++t) acc[t] = (f32x4){0.f, 0.f, 0.f, 0.f};

#pragma unroll
    for (int ks = 0; ks < 4; ++ks) {
        const int slotA = ks * 8 + q * 2, slotB = slotA + 1;
        const int dyA = slotA / 6, dxA = slotA - dyA * 6;
        const int dyB = slotB / 6, dxB = slotB - dyB * 6;
        const int trA = min(py0 + dyA, 11), trB = min(py0 + dyB, 11);
        const int tcA = px0 + dxA, tcB = px0 + dxB;
#pragma unroll
        for (int t = 0; t < 4; ++t) {
            uint2 w8;
            w8.x = pad[(t * 12 + trA) * 16 + tcA];
            w8.y = pad[(t * 12 + trB) * 16 + tcB];
            const short8 Bf = bytes_to_bf16x8(w8);
#pragma unroll
            for (int s = 0; s < 3; ++s)
                acc[t] = __builtin_amdgcn_mfma_f32_16x16x32_bf16(
                    Af[s * 4 + ks], Bf, acc[t], 0, 0, 0);
        }
    }

    // D: col = n = pixel, row = q*4+rr = oc
    const int y = ty * 8 + py0, x = tx * 8 + px0;
    const size_t ub = (size_t)tc * PLANE_U;
#pragma unroll
    for (int rr = 0; rr < 4; ++rr) {
        const int oc = q * 4 + rr;
        const int nb = (bl * 16 + oc) * 1024 + y * 32 + x;
        U[ub + nb] = make_float4(acc[0][rr], acc[1][rr], acc[2][rr], acc[3][rr]);
    }
}

// ---------------------------------------------------------------------------
// conv2 via MFMA (R15, verified): [4t][18][18][16ic] u8, tap-pair K-packing.
// ---------------------------------------------------------------------------
__global__ __launch_bounds__(256) void conv2_mfma_k(
    const unsigned int* __restrict__ s2u, const unsigned short* __restrict__ Wr2,
    float4* __restrict__ U, int b0, int nbl)
{
    __shared__ __align__(16) unsigned char pad[4 * 18 * 18 * 16];   // 20736
    const int tc = blockIdx.x;
    const int bl = blockIdx.z;
    const int b = b0 + bl;
    const int tid = threadIdx.x;
    const int wv = tid >> 6, lane = tid & 63;
    const int q = lane >> 4, n = lane & 15;
    const int PLANE_U = nbl * 8192;      // float4 per chunk

    unsigned int* lp = (unsigned int*)pad;
    for (int i = tid; i < 5184; i += 256) lp[i] = 0u;
    __syncthreads();
    const unsigned int* sb = s2u + (size_t)tc * 32768 + b * 4096;
    for (int e = tid; e < 4096; e += 256) {
        const unsigned int v = sb[e];
        const int c = e >> 8, pix = e & 255;
        const int base = (((pix >> 4) + 1) * 18 + ((pix & 15) + 1)) * 16 + c;
        pad[base]         = (unsigned char)(v & 0xFFu);
        pad[5184 + base]  = (unsigned char)((v >> 8) & 0xFFu);
        pad[10368 + base] = (unsigned char)((v >> 16) & 0xFFu);
        pad[15552 + base] = (unsigned char)(v >> 24);
    }
    __syncthreads();

    for (int i = 0; i < 4; ++i) {
        const int r = wv * 4 + i;        // pixel row (N-tile)
        f32x4 acc[2][4];                 // [oc-tile][t]
#pragma unroll
        for (int mt = 0; mt < 2; ++mt)
#pragma unroll
            for (int t = 0; t < 4; ++t) acc[mt][t] = (f32x4){0.f, 0.f, 0.f, 0.f};

        for (int kp = 0; kp < 5; ++kp) {
            short8 Af[6];   // [s][mt]
#pragma unroll
            for (int s = 0; s < 3; ++s)
#pragma unroll
                for (int mt = 0; mt < 2; ++mt)
                    Af[s * 2 + mt] = *(const short8*)(Wr2 + ((((s * 5 + kp) * 2 + mt) * 64 + lane) * 8));
            int tap = kp * 2 + (q >> 1);
            if (tap > 8) tap = 8;        // pad step: A is zero, address just valid
            const int dy = tap / 3, dx = tap % 3;
#pragma unroll
            for (int t = 0; t < 4; ++t) {
                const int off = ((t * 18 + r + dy) * 18 + (n + dx)) * 16 + (q & 1) * 8;
                const short8 Bf = bytes_to_bf16x8(*(const uint2*)(pad + off));
#pragma unroll
                for (int s = 0; s < 3; ++s)
#pragma unroll
                    for (int mt = 0; mt < 2; ++mt)
                        acc[mt][t] = __builtin_amdgcn_mfma_f32_16x16x32_bf16(
                            Af[s * 2 + mt], Bf, acc[mt][t], 0, 0, 0);
            }
        }

        const size_t ub = (size_t)tc * PLANE_U;
#pragma unroll
        for (int mt = 0; mt < 2; ++mt)
#pragma unroll
            for (int rr = 0; rr < 4; ++rr) {
                const int oc = mt * 16 + q * 4 + rr;
                const int nb = (bl * 32 + oc) * 256 + r * 16 + n;
                U[ub + nb] = make_float4(acc[mt][0][rr], acc[mt][1][rr], acc[mt][2][rr], acc[mt][3][rr]);
            }
    }
}

// ---------------------------------------------------------------------------
// conv3 via MFMA (R14, verified): [4t][10][10][32ic] u8 tile, k = tap*32+ic.
// ---------------------------------------------------------------------------
__global__ __launch_bounds__(256) void conv3_mfma_k(
    const unsigned int* __restrict__ s4u, const unsigned short* __restrict__ Wr,
    float4* __restrict__ U)
{
    __shared__ __align__(16) unsigned char pad[12800];   // [t][row10][col10][ic32]
    const int tc = blockIdx.x;
    const int bl = blockIdx.z;
    const int tid = threadIdx.x;
    const int wv = tid >> 6, lane = tid & 63;
    const int q = lane >> 4, n = lane & 15;

    unsigned int* lp = (unsigned int*)pad;
    for (int i = tid; i < 3200; i += 256) lp[i] = 0u;
    __syncthreads();
    const unsigned int* sb = s4u + (size_t)tc * 16384 + bl * 2048;
    for (int e = tid; e < 2048; e += 256) {
        const unsigned int v = sb[e];
        const int c = e >> 6, pix = e & 63;
        const int base = (((pix >> 3) + 1) * 10 + ((pix & 7) + 1)) * 32 + c;
        pad[base]        = (unsigned char)(v & 0xFFu);
        pad[3200 + base] = (unsigned char)((v >> 8) & 0xFFu);
        pad[6400 + base] = (unsigned char)((v >> 16) & 0xFFu);
        pad[9600 + base] = (unsigned char)(v >> 24);
    }
    __syncthreads();

    const int pixel = wv * 16 + n;
    const int py0 = pixel >> 3, px0 = pixel & 7;

    f32x4 acc[4][4];   // [oc-tile][t]
#pragma unroll
    for (int mt = 0; mt < 4; ++mt)
#pragma unroll
        for (int t = 0; t < 4; ++t) acc[mt][t] = (f32x4){0.f, 0.f, 0.f, 0.f};

    for (int ks = 0; ks < 9; ++ks) {
        const int dy = ks / 3, dx = ks % 3;
        short8 Af[12];
#pragma unroll
        for (int s = 0; s < 3; ++s)
#pragma unroll
            for (int mt = 0; mt < 4; ++mt)
                Af[s * 4 + mt] = *(const short8*)(Wr + ((((s * 9 + ks) * 4 + mt) * 64 + lane) * 8));
#pragma unroll
        for (int t = 0; t < 4; ++t) {
            const int off = ((t * 10 + py0 + dy) * 10 + (px0 + dx)) * 32 + q * 8;
            const short8 Bf = bytes_to_bf16x8(*(const uint2*)(pad + off));
#pragma unroll
            for (int s = 0; s < 3; ++s)
#pragma unroll
                for (int mt = 0; mt < 4; ++mt)
                    acc[mt][t] = __builtin_amdgcn_mfma_f32_16x16x32_bf16(
                        Af[s * 4 + mt], Bf, acc[mt][t], 0, 0, 0);
        }
    }

    const size_t ub = (size_t)tc * 32768 + (size_t)bl * 4096;
#pragma unroll
    for (int mt = 0; mt < 4; ++mt)
#pragma unroll
        for (int r = 0; r < 4; ++r) {
            const int oc = mt * 16 + q * 4 + r;
            const int nb = oc * 64 + wv * 16 + n;
            U[ub + nb] = make_float4(acc[mt][0][r], acc[mt][1][r], acc[mt][2][r], acc[mt][3][r]);
        }
}

// ---------------------------------------------------------------------------
// spike body: per-neuron scan. float4 per chunk in, uchar4 per chunk out.
// ---------------------------------------------------------------------------
__device__ __forceinline__ void spike_body(
    const float4* __restrict__ U, uchar4* __restrict__ S,
    int nneur, int sstride, int soff, const RefK& rk)
{
    const int n = blockIdx.x * 64 + threadIdx.x;
    const float4* up = U + n;
    uchar4* sp = S + soff + n;
    float buf[10];
#pragma unroll
    for (int r = 0; r < 10; ++r) buf[r] = 0.f;

    float4 ring[8];
#pragma unroll
    for (int r = 0; r < 8; ++r) ring[r] = up[(size_t)r * nneur];

#pragma unroll 8
    for (int ch = 0; ch < 72; ++ch) {
        const float4 cur = ring[ch & 7];
        const int pf = (ch + 8 < NCHUNK) ? ch + 8 : NCHUNK - 1;
        ring[ch & 7] = up[(size_t)pf * nneur];
        uchar4 o;
        o.x = spike_step(cur.x, buf, rk);
        o.y = spike_step(cur.y, buf, rk);
        o.z = spike_step(cur.z, buf, rk);
        o.w = spike_step(cur.w, buf, rk);
        sp[(size_t)ch * sstride] = o;
    }
#pragma unroll
    for (int ch = 72; ch < NCHUNK; ++ch) {
        const float4 cur = ring[ch & 7];
        uchar4 o;
        o.x = spike_step(cur.x, buf, rk);
        o.y = spike_step(cur.y, buf, rk);
        o.z = spike_step(cur.z, buf, rk);
        o.w = spike_step(cur.w, buf, rk);
        sp[(size_t)ch * sstride] = o;
    }
}

__global__ __launch_bounds__(64) void spike1_k(
    const float4* U, uchar4* S, int nneur, int sstride, int soff, RefK rk)
{ spike_body(U, S, nneur, sstride, soff, rk); }

__global__ __launch_bounds__(64) void spike2_k(
    const float4* U, uchar4* S, int nneur, int sstride, int soff, RefK rk)
{ spike_body(U, S, nneur, sstride, soff, rk); }

__global__ __launch_bounds__(64) void spike3_k(
    const float4* U, uchar4* S, int nneur, int sstride, int soff, RefK rk)
{ spike_body(U, S, nneur, sstride, soff, rk); }

// ---------------------------------------------------------------------------
// pool(2)*11 + spike. Two 8-byte loads per chunk (x-pair rows). Ring-8.
// ---------------------------------------------------------------------------
__device__ __forceinline__ int bsum4(uint2 r0, uint2 r1, int k) {
    return (int)((r0.x >> (8 * k)) & 0xffu) + (int)((r0.y >> (8 * k)) & 0xffu)
         + (int)((r1.x >> (8 * k)) & 0xffu) + (int)((r1.y >> (8 * k)) & 0xffu);
}

template <int C, int H, int W>
__device__ __forceinline__ void pool_body(
    const uchar4* __restrict__ Sin, uchar4* __restrict__ Sout, const RefK& rk)
{
    constexpr int H2 = H / 2, W2 = W / 2;
    constexpr int SIN = 8 * C * H * W;     // chunk stride (uchar4 units)
    constexpr int SOUT = 8 * C * H2 * W2;
    const int n = blockIdx.x * 64 + threadIdx.x;   // exact multiple of 64
    const int x = n % W2;
    const int y = (n / W2) % H2;
    const int c = (n / (W2 * H2)) % C;
    const int b = n / (W2 * H2 * C);
    const int base = (((b * C + c) * H + 2 * y) * W + 2 * x);
    uchar4* q = Sout + n;

    float buf[10];
#pragma unroll
    for (int r = 0; r < 10; ++r) buf[r] = 0.f;

    uint2 r0[8], r1[8];
#pragma unroll
    for (int r = 0; r < 8; ++r) {
        r0[r] = *(const uint2*)(Sin + (size_t)r * SIN + base);
        r1[r] = *(const uint2*)(Sin + (size_t)r * SIN + base + W);
    }

#pragma unroll 8
    for (int ch = 0; ch < 72; ++ch) {
        const uint2 a0 = r0[ch & 7], a1 = r1[ch & 7];
        const int pf = (ch + 8 < NCHUNK) ? ch + 8 : NCHUNK - 1;
        r0[ch & 7] = *(const uint2*)(Sin + (size_t)pf * SIN + base);
        r1[ch & 7] = *(const uint2*)(Sin + (size_t)pf * SIN + base + W);
        uchar4 o;
        o.x = spike_step(11.0f * (float)bsum4(a0, a1, 0), buf, rk);
        o.y = spike_step(11.0f * (float)bsum4(a0, a1, 1), buf, rk);
        o.z = spike_step(11.0f * (float)bsum4(a0, a1, 2), buf, rk);
        o.w = spike_step(11.0f * (float)bsum4(a0, a1, 3), buf, rk);
        q[(size_t)ch * SOUT] = o;
    }
#pragma unroll
    for (int ch = 72; ch < NCHUNK; ++ch) {
        const uint2 a0 = r0[ch & 7], a1 = r1[ch & 7];
        uchar4 o;
        o.x = spike_step(11.0f * (float)bsum4(a0, a1, 0), buf, rk);
        o.y = spike_step(11.0f * (float)bsum4(a0, a1, 1), buf, rk);
        o.z = spike_step(11.0f * (float)bsum4(a0, a1, 2), buf, rk);
        o.w = spike_step(11.0f * (float)bsum4(a0, a1, 3), buf, rk);
        q[(size_t)ch * SOUT] = o;
    }
}

__global__ __launch_bounds__(64) void pool2_k(
    const uchar4* Sin, uchar4* Sout, RefK rk) { pool_body<16, 32, 32>(Sin, Sout, rk); }
__global__ __launch_bounds__(64) void pool4_k(
    const uchar4* Sin, uchar4* Sout, RefK rk) { pool_body<32, 16, 16>(Sin, Sout, rk); }

// ---------------------------------------------------------------------------
// dense u: U6[tc][b*10+o][4] = sum_site wfc[o,site] * s5[tc][b*4096+site][4]
// ---------------------------------------------------------------------------
__global__ __launch_bounds__(64) void dense_k(
    const uchar4* __restrict__ S5, const float* __restrict__ WFC,
    float4* __restrict__ U6)
{
    const int tc = blockIdx.x, o = blockIdx.y, b = blockIdx.z;
    const int lane = threadIdx.x;
    float a0 = 0.f, a1 = 0.f, a2 = 0.f, a3 = 0.f;
    const uchar4* sb = S5 + (size_t)tc * 32768 + b * 4096;
    const float* wb = WFC + o * 4096;
    for (int i = 0; i < 64; ++i) {
        const int site = i * 64 + lane;
        const uchar4 s = sb[site];
        const float w = wb[site];
        a0 = fmaf(w, (float)s.x, a0);
        a1 = fmaf(w, (float)s.y, a1);
        a2 = fmaf(w, (float)s.z, a2);
        a3 = fmaf(w, (float)s.w, a3);
    }
#pragma unroll
    for (int m = 1; m < 64; m <<= 1) {
        a0 += __shfl_xor(a0, m, 64);
        a1 += __shfl_xor(a1, m, 64);
        a2 += __shfl_xor(a2, m, 64);
        a3 += __shfl_xor(a3, m, 64);
    }
    if (lane == 0)
        U6[(size_t)tc * 80 + b * 10 + o] = make_float4(a0, a1, a2, a3);
}

// final spike over 80 neurons; float4 chunks in, [n][t] fp32 out.
__global__ __launch_bounds__(128) void spike6_k(
    const float4* __restrict__ U6, float* __restrict__ Out, RefK rk)
{
    const int n = threadIdx.x;
    if (n >= 80) return;
    const float4* up = U6 + n;
    float* op = Out + (size_t)n * T_SAMPLE;
    float buf[10];
#pragma unroll
    for (int r = 0; r < 10; ++r) buf[r] = 0.f;

    float4 ring[8];
#pragma unroll
    for (int r = 0; r < 8; ++r) ring[r] = up[(size_t)r * 80];

#pragma unroll 8
    for (int ch = 0; ch < 72; ++ch) {
        const float4 cur = ring[ch & 7];
        const int pf = (ch + 8 < NCHUNK) ? ch + 8 : NCHUNK - 1;
        ring[ch & 7] = up[(size_t)pf * 80];
        float4 o;
        o.x = (float)spike_step(cur.x, buf, rk);
        o.y = (float)spike_step(cur.y, buf, rk);
        o.z = (float)spike_step(cur.z, buf, rk);
        o.w = (float)spike_step(cur.w, buf, rk);
        *(float4*)(op + ch * 4) = o;
    }
#pragma unroll
    for (int ch = 72; ch < NCHUNK; ++ch) {
        const float4 cur = ring[ch & 7];
        float4 o;
        o.x = (float)spike_step(cur.x, buf, rk);
        o.y = (float)spike_step(cur.y, buf, rk);
        o.z = (float)spike_step(cur.z, buf, rk);
        o.w = (float)spike_step(cur.w, buf, rk);
        *(float4*)(op + ch * 4) = o;
    }
}

extern "C" void kernel_launch(void* const* d_in, const int* in_sizes, int n_in,
                              void* d_out, int out_size, void* d_ws, size_t ws_size,
                              hipStream_t stream)
{
    const float* spikeIn = (const float*)d_in[0];  // [8,2,34,34,300]
    const float* w1 = (const float*)d_in[1];       // [16,2,5,5]
    const float* w2 = (const float*)d_in[2];       // [32,16,3,3]
    const float* w3 = (const float*)d_in[3];       // [64,32,3,3]
    const float* wfc = (const float*)d_in[4];      // [10,64,8,8]
    float* out = (float*)d_out;                    // [8,10,1,1,300]

    RefK rk;
    for (int t = 1; t <= 10; ++t)
        rk.v[t - 1] = (float)(-20.0 * (double)t * std::exp(1.0 - (double)t));

    // workspace tiers (U region first, then A, B, U6):
    //   huge: U 157.3 MB -> conv1/spike1 single launches (nbl1=8)
    //   big : U  78.6 MB -> conv1 x2, conv2 single
    //   small: U 39.3 MB -> conv1 x4, conv2 x2
    // LIFETIME-CORRECT weight-frag placement (R16 bug: A region is s1 during
    // layer 1!):
    //   Wr1 (conv1, 12 KB): B region at X_end (B+5.55 MB) - free during
    //     layer 1; s2 overwrites later (conv1 done by then).
    //   Wr (conv3) / Wr2 (conv2): A+20 MB, prepped AFTER pool2 (s1 dead;
    //     s3 ends at 19.66 MB, s5 at 9.83 MB - never touched again).
    const size_t A_BYTES = 39321600;
    const size_t B_BYTES = 9830400;
    const size_t U6_BYTES = 96000;
    const size_t U_HUGE = 157286400, U_BIG = 78643200, U_SMALL = 39321600;
    const size_t TAIL = A_BYTES + B_BYTES + U6_BYTES;
    const bool huge = ws_size >= U_HUGE + TAIL;
    const bool big = ws_size >= U_BIG + TAIL;
    const size_t U_BYTES = huge ? U_HUGE : (big ? U_BIG : U_SMALL);

    char* ws = (char*)d_ws;
    float4* U = (float4*)ws;
    uchar4* A = (uchar4*)(ws + U_BYTES);
    uchar4* Bb = (uchar4*)(ws + U_BYTES + A_BYTES);
    float4* U6 = (float4*)(ws + U_BYTES + A_BYTES + B_BYTES);
    unsigned short* Wr = (unsigned short*)(ws + U_BYTES + 20971520);            // A+20MB
    unsigned short* Wr2 = (unsigned short*)(ws + U_BYTES + 20971520 + 131072);  // A+20MB+128K
    unsigned short* Wr1 = (unsigned short*)(ws + U_BYTES + A_BYTES + 5570560);  // B+5.57MB (past X)

    uchar4* X = Bb;   // 5.549 MB; dead after layer 1
    uchar4* s1 = A;
    uchar4* s2 = Bb;
    uchar4* s3 = A;   // s1 dead after pool2
    uchar4* s4 = Bb;  // s2 dead after conv2-u
    uchar4* s5 = A;   // s3 dead after pool4

    // ---- input transpose + conv1 weight prep (Wr1 in B free tail) ----
    transpose_in_k<<<18496 / 16, 256, 0, stream>>>(spikeIn, (unsigned int*)X);
    prep_w1_k<<<24, 256, 0, stream>>>(w1, Wr1);

    // ---- layer 1: MFMA conv(2->16, k5) + spike ----
    const int nbl1 = huge ? 8 : (big ? 4 : 2);
    for (int b0 = 0; b0 < 8; b0 += nbl1) {
        dim3 g1(NCHUNK, 16, nbl1);  // 16 tiles of 8x8
        conv1_mfma_k<<<g1, 256, 0, stream>>>((const unsigned int*)X, Wr1, U, b0, nbl1);
        const int nn = nbl1 * 16384;
        spike1_k<<<nn / 64, 64, 0, stream>>>(U, s1, nn, 131072, b0 * 16384, rk);
    }
    // ---- pool2 + spike ----
    pool2_k<<<32768 / 64, 64, 0, stream>>>(s1, s2, rk);
    // ---- conv2/conv3 weight preps (A+20MB region dead from here on) ----
    prep_w2_k<<<60, 256, 0, stream>>>(w2, Wr2);
    prep_w3_k<<<216, 256, 0, stream>>>(w3, Wr);
    // ---- layer 2: MFMA conv(16->32, k3) + spike ----
    const int nbl2 = (huge || big) ? 8 : 4;
    for (int b0 = 0; b0 < 8; b0 += nbl2) {
        dim3 g2(NCHUNK, 1, nbl2);
        conv2_mfma_k<<<g2, 256, 0, stream>>>((const unsigned int*)s2, Wr2, U, b0, nbl2);
        const int nn = nbl2 * 8192;
        spike2_k<<<nn / 64, 64, 0, stream>>>(U, s3, nn, 65536, b0 * 8192, rk);
    }
    // ---- pool4 + spike ----
    pool4_k<<<16384 / 64, 64, 0, stream>>>(s3, s4, rk);
    // ---- layer 3: MFMA conv(32->64, k3) + spike, full batch ----
    {
        dim3 g3(NCHUNK, 1, 8);   // (tc, -, bl): 600 blocks
        conv3_mfma_k<<<g3, 256, 0, stream>>>((const unsigned int*)s4, Wr, U);
        spike3_k<<<32768 / 64, 64, 0, stream>>>(U, s5, 32768, 32768, 0, rk);
    }
    // ---- dense + final spike ----
    dim3 g6(NCHUNK, 10, 8);
    dense_k<<<g6, 64, 0, stream>>>(s5, wfc, U6);
    spike6_k<<<1, 128, 0, stream>>>(U6, out, rk);
}